// Round 6
// baseline (932.630 us; speedup 1.0000x reference)
//
#include <hip/hip_runtime.h>
#include <hip/hip_fp16.h>

// Problem constants (reference: B=16, T=2048, D=768)
#define DD 768
#define BB 16
#define TT 2048
#define BT (BB*TT)   // 32768
#define NQC 8        // 256-row blocks per batch for column-softmax stats

using u16 = unsigned short;
using f16 = _Float16;
typedef __attribute__((ext_vector_type(8))) f16 half8;   // MFMA A/B frag (4 VGPR)
typedef __attribute__((ext_vector_type(4))) f16 half4;   // 8B store
typedef __attribute__((ext_vector_type(4))) float f32x4; // MFMA C/D frag

typedef const __attribute__((address_space(1))) unsigned int* gas1;
typedef __attribute__((address_space(3))) unsigned int* las3;
__device__ __forceinline__ void gload16(const void* g, void* l){
  // async global->LDS, 16B per lane; LDS dest linear in lane order (wave base + lane*16)
  __builtin_amdgcn_global_load_lds((gas1)g, (las3)l, 16, 0, 0);
}

// ---------------- fp32 -> fp16 ----------------
__global__ __launch_bounds__(256)
void tofp16_kernel(const float* __restrict__ src, f16* __restrict__ dst, int n4){
  const int stride = gridDim.x * 256;
  for (int i = blockIdx.x*256 + threadIdx.x; i < n4; i += stride){
    float4 v = ((const float4*)src)[i];
    half4 h; h[0]=(f16)v.x; h[1]=(f16)v.y; h[2]=(f16)v.z; h[3]=(f16)v.w;
    ((half4*)dst)[i] = h;
  }
}

// =================================================================
// 256x256 NT GEMM, 512 threads (8 waves 2Mx4N), BK=32, 4-deep LDS
// pipeline with counted vmcnt (prefetch survives raw s_barrier).
// XOR-swizzled LDS slots: conflict-free ds_read_b128.
// OMODE 0: merged QKV proj. z=proj: B=W[z], out f16 +bias -> base+{0,oz1,oz2}
// OMODE 1: S logits: out f32 + fused column-stats partials -> f0=pm,f1=pz
// OMODE 2: PV: z=batch, out f32 = acc + aux[flat residual]
// =================================================================
template<int OMODE>
__global__ __launch_bounds__(512, 1)
void gemm256(const f16* __restrict__ A, int lda, long sA,
             const f16* __restrict__ B, int ldb, long sB,
             void* __restrict__ Out, int ldc, long sC, long oz1, long oz2,
             const float* __restrict__ aux, int Kdim,
             float* __restrict__ f0, float* __restrict__ f1)
{
  __shared__ f16 lA[4][256*32];    // 64 KB
  __shared__ f16 lB[4][256*32];    // 64 KB
  __shared__ float sst[1024];      // 4 KB stats scratch (OMODE 1)

  const int b = blockIdx.z;
  const f16* A_ = A + (size_t)b * sA;
  const f16* B_ = B + (size_t)b * sB;
  const int m0 = blockIdx.x * 256, n0 = blockIdx.y * 256;
  const int tid = threadIdx.x, lane = tid & 63, wave = tid >> 6;
  const int wm = wave >> 2, wn = wave & 3;

  // staging: 2 chunks per operand per tile; chunk c -> row=c>>2, dest slot=c&3,
  // source slot = dest ^ g(row), g(r) = (r&3)^((r>>2)&3)  [involution]
  const int c0 = tid, c1 = 512 + tid;
  const int r0 = c0 >> 2, s0 = (c0 & 3) ^ ((r0 & 3) ^ ((r0 >> 2) & 3));
  const int r1 = c1 >> 2, s1 = (c1 & 3) ^ ((r1 & 3) ^ ((r1 >> 2) & 3));
  const size_t ga0 = (size_t)(m0 + r0) * lda + s0 * 8;
  const size_t ga1 = (size_t)(m0 + r1) * lda + s1 * 8;
  const size_t gb0 = (size_t)(n0 + r0) * ldb + s0 * 8;
  const size_t gb1 = (size_t)(n0 + r1) * ldb + s1 * 8;

  f32x4 acc[8][4] = {};
  const int NT = Kdim >> 5;

  auto STAGE = [&](int u, int kt){
    f16* dA = &lA[u][0]; f16* dB = &lB[u][0];
    gload16(A_ + ga0 + kt, dA + c0*8);
    gload16(A_ + ga1 + kt, dA + c1*8);
    gload16(B_ + gb0 + kt, dB + c0*8);
    gload16(B_ + gb1 + kt, dB + c1*8);
  };

  STAGE(0, 0); STAGE(1, 32); STAGE(2, 64);   // 12 loads in flight

  // frag read addresses (swizzled): row = base + frow, slot = kslot ^ g(frow)
  const int frow = lane & 15;
  const int rsl = (((lane >> 4) ^ ((frow & 3) ^ ((frow >> 2) & 3))) & 3) * 8;
  const f16* pA = &lA[0][0] + (wm*128 + frow)*32 + rsl;
  const f16* pB = &lB[0][0] + (wn*64  + frow)*32 + rsl;

  for (int t = 0; t < NT; ++t){
    const int u = t & 3;
    __builtin_amdgcn_s_barrier();            // all waves done reading buf[(t+3)&3]
    if (t + 3 < NT) STAGE((t + 3) & 3, (t + 3) * 32);
    const int rem = NT - 1 - t;
    if (rem >= 3)      asm volatile("s_waitcnt vmcnt(12)" ::: "memory");
    else if (rem == 2) asm volatile("s_waitcnt vmcnt(8)"  ::: "memory");
    else if (rem == 1) asm volatile("s_waitcnt vmcnt(4)"  ::: "memory");
    else               asm volatile("s_waitcnt vmcnt(0)"  ::: "memory");
    __builtin_amdgcn_s_barrier();            // everyone's tile-t loads landed
    __builtin_amdgcn_sched_barrier(0);

    const f16* tA = pA + u * 8192;
    const f16* tB = pB + u * 8192;
    half8 af[8], bf[4];
#pragma unroll
    for (int i = 0; i < 8; ++i) af[i] = *(const half8*)(tA + i*512);
#pragma unroll
    for (int j = 0; j < 4; ++j) bf[j] = *(const half8*)(tB + j*512);
    __builtin_amdgcn_s_setprio(1);
#pragma unroll
    for (int i = 0; i < 8; ++i)
#pragma unroll
      for (int j = 0; j < 4; ++j)
        acc[i][j] = __builtin_amdgcn_mfma_f32_16x16x32_f16(af[i], bf[j], acc[i][j], 0,0,0);
    __builtin_amdgcn_s_setprio(0);
  }

  // epilogue; C/D: col = lane&15 (=frow), row = (lane>>4)*4 + r  [m89 verified]
  const int kq4 = (lane >> 4) * 4;
  if constexpr (OMODE == 0){
    f16* O = (f16*)Out + (b == 0 ? 0l : b == 1 ? oz1 : oz2);
#pragma unroll
    for (int j = 0; j < 4; ++j){
      const int gc = n0 + wn*64 + j*16 + frow;
      const float bias_v = aux[b*DD + gc];
#pragma unroll
      for (int i = 0; i < 8; ++i)
#pragma unroll
        for (int r = 0; r < 4; ++r){
          const int gr = m0 + wm*128 + i*16 + kq4 + r;
          O[(size_t)gr*ldc + gc] = (f16)(acc[i][j][r] + bias_v);
        }
    }
  } else if constexpr (OMODE == 2){
    float* O = (float*)Out + (size_t)b * sC;
    const float* R = aux + (size_t)b * sC;
#pragma unroll
    for (int j = 0; j < 4; ++j){
      const int gc = n0 + wn*64 + j*16 + frow;
#pragma unroll
      for (int i = 0; i < 8; ++i)
#pragma unroll
        for (int r = 0; r < 4; ++r){
          const int gr = m0 + wm*128 + i*16 + kq4 + r;
          const size_t o = (size_t)gr*ldc + gc;
          O[o] = acc[i][j][r] + R[o];
        }
    }
  } else {
    float* S_ = (float*)Out + (size_t)b * sC;
#pragma unroll
    for (int j = 0; j < 4; ++j){
      const int gc = n0 + wn*64 + j*16 + frow;
      float mx = -3.0e38f;
#pragma unroll
      for (int i = 0; i < 8; ++i)
#pragma unroll
        for (int r = 0; r < 4; ++r){
          const int gr = m0 + wm*128 + i*16 + kq4 + r;
          S_[(size_t)gr*ldc + gc] = acc[i][j][r];
          mx = fmaxf(mx, acc[i][j][r]);
        }
      float zz = 0.f;
#pragma unroll
      for (int i = 0; i < 8; ++i)
#pragma unroll
        for (int r = 0; r < 4; ++r) zz += __expf(acc[i][j][r] - mx);
      // butterfly over lane bits 4,5: reduce the 4 row-groups of a column
#pragma unroll
      for (int off = 16; off < 64; off <<= 1){
        float mo = __shfl_xor(mx, off, 64);
        float zo = __shfl_xor(zz, off, 64);
        float M = fmaxf(mx, mo);
        zz = zz*__expf(mx - M) + zo*__expf(mo - M);
        mx = M;
      }
      if (lane < 16){
        sst[wave*64 + j*16 + lane] = mx;
        sst[512 + wave*64 + j*16 + lane] = zz;
      }
    }
    __syncthreads();
    if (wm == 0 && lane < 16){     // waves 0..3 merge partner waves 4..7 (same wn)
#pragma unroll
      for (int j = 0; j < 4; ++j){
        float ma = sst[wave*64 + j*16 + lane],     za = sst[512 + wave*64 + j*16 + lane];
        float mb = sst[(wave+4)*64 + j*16 + lane], zb = sst[512 + (wave+4)*64 + j*16 + lane];
        float M = fmaxf(ma, mb);
        float Z = za*__expf(ma - M) + zb*__expf(mb - M);
        const int gc = n0 + wn*64 + j*16 + lane;
        size_t o = ((size_t)b * NQC + blockIdx.x) * TT + gc;
        f0[o] = M; f1[o] = Z;
      }
    }
  }
}

// ------- merge NQC row-block partials per column -> mcol, zinv -------
__global__ __launch_bounds__(256)
void statsB_kernel(const float* __restrict__ pm, const float* __restrict__ pz,
                   float* __restrict__ mcol, float* __restrict__ zinv){
  const int b = blockIdx.y;
  const int t = blockIdx.x * 256 + threadIdx.x;
  float M = -3.0e38f;
#pragma unroll
  for (int k = 0; k < NQC; ++k)
    M = fmaxf(M, pm[((size_t)b * NQC + k) * TT + t]);
  float Z = 0.f;
#pragma unroll
  for (int k = 0; k < NQC; ++k){
    size_t o = ((size_t)b * NQC + k) * TT + t;
    Z += pz[o] * __expf(pm[o] - M);
  }
  mcol[b*TT + t] = M;
  zinv[b*TT + t] = 1.f / (Z * 27.712812921102035f);  // 1/(Z*sqrt(768))
}

// ---------------- P = exp(S - m_t) * zinv_t -> f16 ----------------
__global__ __launch_bounds__(256)
void pexp_kernel(const float* __restrict__ S, const float* __restrict__ mcol,
                 const float* __restrict__ zinv, f16* __restrict__ P, int G){
  const int n4 = G * (TT*TT/4);
  const int stride = gridDim.x * 256;
  for (int i = blockIdx.x*256 + threadIdx.x; i < n4; i += stride){
    float4 s4 = ((const float4*)S)[i];
    int t   = (i*4) & (TT - 1);
    int row = (int)(((size_t)i * 4) >> 11);   // row within chunk
    int b   = row >> 11;                      // local batch
    int bt = b * TT + t;
    float4 m4 = *(const float4*)&mcol[bt];
    float4 z4 = *(const float4*)&zinv[bt];
    half4 o;
    o[0] = (f16)(__expf(s4.x - m4.x) * z4.x);
    o[1] = (f16)(__expf(s4.y - m4.y) * z4.y);
    o[2] = (f16)(__expf(s4.z - m4.z) * z4.z);
    o[3] = (f16)(__expf(s4.w - m4.w) * z4.w);
    ((half4*)P)[i] = o;
  }
}

// ---------------- V [t,v] -> Vt [v,t] (per local batch z) ----------------
__global__ __launch_bounds__(256)
void transp_kernel(const u16* __restrict__ V, u16* __restrict__ Vt){
  const int b = blockIdx.z;
  const int t0 = blockIdx.x * 64, v0 = blockIdx.y * 64;
  const u16* Vb = V + (size_t)b * TT * DD;
  u16* Vtb = Vt + (size_t)b * DD * TT;
  __shared__ u16 tile[64][66];
  const int tid = threadIdx.x;
#pragma unroll
  for (int i = 0; i < 4; ++i){
    int c = i*256 + tid;
    int r = c >> 4, c4 = (c & 15) * 4;
    ushort4 u = *(const ushort4*)&Vb[(size_t)(t0 + r) * DD + v0 + c4];
    tile[r][c4+0] = u.x; tile[r][c4+1] = u.y; tile[r][c4+2] = u.z; tile[r][c4+3] = u.w;
  }
  __syncthreads();
#pragma unroll
  for (int i = 0; i < 4; ++i){
    int c = i*256 + tid;
    int vr = c >> 4, t4 = (c & 15) * 4;
    ushort4 u;
    u.x = tile[t4+0][vr]; u.y = tile[t4+1][vr]; u.z = tile[t4+2][vr]; u.w = tile[t4+3][vr];
    *(ushort4*)&Vtb[(size_t)(v0 + vr) * TT + t0 + t4] = u;
  }
}

// ---------------- LayerNorm (in-place on d_out), one row per block ----------------
__global__ __launch_bounds__(256)
void ln_kernel(float* __restrict__ y, const float* __restrict__ gamma,
               const float* __restrict__ beta){
  const int row = blockIdx.x;
  float* p = y + (size_t)row * DD;
  const int tid = threadIdx.x;
  float v[3]; float s = 0.f, sq = 0.f;
#pragma unroll
  for (int k = 0; k < 3; ++k){
    v[k] = p[tid + k*256];
    s += v[k]; sq += v[k]*v[k];
  }
#pragma unroll
  for (int off = 32; off > 0; off >>= 1){
    s  += __shfl_down(s,  off, 64);
    sq += __shfl_down(sq, off, 64);
  }
  __shared__ float red[8];
  const int lane = tid & 63, w = tid >> 6;
  if (lane == 0){ red[w] = s; red[4+w] = sq; }
  __syncthreads();
  if (tid == 0){
    red[0] = red[0]+red[1]+red[2]+red[3];
    red[4] = red[4]+red[5]+red[6]+red[7];
  }
  __syncthreads();
  const float mu  = red[0] * (1.f/DD);
  const float var = red[4] * (1.f/DD) - mu*mu;
  const float rs  = rsqrtf(var + 1e-5f);
#pragma unroll
  for (int k = 0; k < 3; ++k){
    int c = tid + k*256;
    p[c] = (v[k] - mu) * rs * gamma[c] + beta[c];
  }
}

extern "C" void kernel_launch(void* const* d_in, const int* in_sizes, int n_in,
                              void* d_out, int out_size, void* d_ws, size_t ws_size,
                              hipStream_t stream)
{
  // setup_inputs order: x, Wk, bk, Wq, bq, Wv, bv, gamma, beta
  const float* x    = (const float*)d_in[0];
  const float* Wk   = (const float*)d_in[1];
  const float* bk   = (const float*)d_in[2];
  const float* Wq   = (const float*)d_in[3];
  const float* bq   = (const float*)d_in[4];
  const float* Wv   = (const float*)d_in[5];
  const float* bv   = (const float*)d_in[6];
  const float* gamma= (const float*)d_in[7];
  const float* beta = (const float*)d_in[8];
  float* out = (float*)d_out;

  const size_t PW  = (size_t)DD*DD*2;    // f16 weight plane
  const size_t PB  = (size_t)TT*DD*2;    // f16 activation plane per batch
  const size_t SCB = (size_t)TT*TT*4;    // f32 S per batch
  auto al = [](size_t n){ return (n + 255) & ~(size_t)255; };

  // layout: Wf | biasf | Vt(full) | P16(full) | Sc(G, overlays Xc+Vc) | Qc | Kc | pm pz mcol zinv
  auto need = [&](int G)->size_t{
    return al(3*PW) + al(3*DD*4) + al((size_t)BB*PB) + al((size_t)BB*TT*TT*2)
         + al((size_t)G*SCB) + 2*al((size_t)G*PB)
         + 2*al((size_t)G*NQC*TT*4) + 2*al((size_t)G*TT*4);
  };

  int G = 0;
  for (int g : {4, 2, 1}) if (need(g) <= ws_size){ G = g; break; }
  if (G == 0) return;

  char* p = (char*)d_ws;
  auto alloc = [&](size_t n)->char*{ char* r = p; p += (n + 255) & ~(size_t)255; return r; };
  f16*   Wf    = (f16*)alloc(3*PW);            // [Wv; Wq; Wk]
  float* biasf = (float*)alloc(3*DD*4);        // [bv; bq; bk]
  f16*   Vt    = (f16*)alloc((size_t)BB*PB);
  f16*   P16   = (f16*)alloc((size_t)BB*TT*TT*2);
  float* Sc    = (float*)alloc((size_t)G*SCB); // overlays Xc (first G*PB) + Vc (next G*PB)
  f16*   Qc    = (f16*)alloc((size_t)G*PB);
  f16*   Kc    = (f16*)alloc((size_t)G*PB);
  float* pm    = (float*)alloc((size_t)G*NQC*TT*4);
  float* pz    = (float*)alloc((size_t)G*NQC*TT*4);
  float* mcol  = (float*)alloc((size_t)G*TT*4);
  float* zinv  = (float*)alloc((size_t)G*TT*4);
  f16* Xc = (f16*)Sc;
  f16* Vc = (f16*)((char*)Sc + (size_t)G*PB);

  tofp16_kernel<<<288, 256, 0, stream>>>(Wv, Wf,           DD*DD/4);
  tofp16_kernel<<<288, 256, 0, stream>>>(Wq, Wf +   DD*DD, DD*DD/4);
  tofp16_kernel<<<288, 256, 0, stream>>>(Wk, Wf + 2*DD*DD, DD*DD/4);
  hipMemcpyAsync(biasf,        bv, DD*4, hipMemcpyDeviceToDevice, stream);
  hipMemcpyAsync(biasf +   DD, bq, DD*4, hipMemcpyDeviceToDevice, stream);
  hipMemcpyAsync(biasf + 2*DD, bk, DD*4, hipMemcpyDeviceToDevice, stream);

  const long oz1 = (long)(Qc - Vc);   // f16-unit offsets for proj z=1,2 outputs
  const long oz2 = (long)(Kc - Vc);
  const int nRows = G * TT;

  for (int b0 = 0; b0 < BB; b0 += G){
    tofp16_kernel<<<2048, 256, 0, stream>>>(x + (size_t)b0*TT*DD, Xc, nRows*DD/4);

    // merged V,Q,K projections: z = proj index (writes Vc, Qc, Kc)
    dim3 gp(nRows/256, DD/256, 3);
    gemm256<0><<<gp, 512, 0, stream>>>(Xc, DD, 0l, Wf, DD, (long)DD*DD,
                                       Vc, DD, 0l, oz1, oz2, biasf, DD,
                                       nullptr, nullptr);

    transp_kernel<<<dim3(TT/64, DD/64, G), 256, 0, stream>>>(
        (const u16*)Vc, (u16*)(Vt + (size_t)b0*DD*TT));

    // S = Q K^T (f32, overlays Xc/Vc which are now dead) + fused stats partials
    dim3 gs(TT/256, TT/256, G);
    gemm256<1><<<gs, 512, 0, stream>>>(Qc, DD, (long)TT*DD, Kc, DD, (long)TT*DD,
                                       Sc, TT, (long)TT*TT, 0l, 0l, nullptr, DD,
                                       pm, pz);

    statsB_kernel<<<dim3(TT/256, G), 256, 0, stream>>>(pm, pz, mcol, zinv);
    pexp_kernel<<<2048, 256, 0, stream>>>(Sc, mcol, zinv,
                                          P16 + (size_t)b0*TT*TT, G);
  }

  // PV over all batches + residual
  dim3 gpv(TT/256, DD/256, BB);
  gemm256<2><<<gpv, 512, 0, stream>>>(P16, TT, (long)TT*TT, Vt, TT, (long)DD*TT,
                                      out, DD, (long)TT*DD, 0l, 0l, x, TT,
                                      nullptr, nullptr);

  ln_kernel<<<BT, 256, 0, stream>>>(out, gamma, beta);
}

// Round 7
// 813.967 us; speedup vs baseline: 1.1458x; 1.1458x over previous
//
#include <hip/hip_runtime.h>
#include <hip/hip_fp16.h>

// Problem constants (reference: B=16, T=2048, D=768)
#define DD 768
#define BB 16
#define TT 2048
#define BT (BB*TT)   // 32768
#define NQC 16       // 128-row blocks per batch for column-softmax stats

using u16 = unsigned short;
using f16 = _Float16;
typedef __attribute__((ext_vector_type(8))) f16 half8;   // MFMA A/B frag (4 VGPR)
typedef __attribute__((ext_vector_type(4))) f16 half4;   // 8B store
typedef __attribute__((ext_vector_type(4))) float f32x4; // MFMA C/D frag

// XOR involution on 16B slots within a row: spreads K-slots across banks
#define GSWZ(r) ((((r) & 3)) ^ (((r) >> 2) & 3))

typedef const __attribute__((address_space(1))) unsigned int* gas1;
typedef __attribute__((address_space(3))) unsigned int* las3;
__device__ __forceinline__ void gload16(const void* g, void* l){
  // async global->LDS, 16B per lane; LDS dest linear in lane order (wave base + lane*16)
  __builtin_amdgcn_global_load_lds((gas1)g, (las3)l, 16, 0, 0);
}

// ---------------- fp32 -> fp16 ----------------
__global__ __launch_bounds__(256)
void tofp16_kernel(const float* __restrict__ src, f16* __restrict__ dst, int n4){
  const int stride = gridDim.x * 256;
  for (int i = blockIdx.x*256 + threadIdx.x; i < n4; i += stride){
    float4 v = ((const float4*)src)[i];
    half4 h; h[0]=(f16)v.x; h[1]=(f16)v.y; h[2]=(f16)v.z; h[3]=(f16)v.w;
    ((half4*)dst)[i] = h;
  }
}

// =================================================================
// 128x128 NT GEMM, 256 threads (4 waves 2x2), BK=32, 4-deep LDS
// pipeline, counted vmcnt (prefetch survives raw s_barrier),
// 2 blocks/CU (64KB tile LDS), XCD-swizzled tile ids.
// OMODE 0: merged QKV proj. z=proj: B=W[z], out f16 = acc + bias[z]
// OMODE 1: S logits: out f32 + fused column-stats partials (f0=pm,f1=pz)
// OMODE 2: PV: z=batch, out f32 = acc + aux[flat residual]
// =================================================================
template<int OMODE>
__global__ __launch_bounds__(256, 2)
void gemmk(const f16* __restrict__ A, int lda, long sA,
           const f16* __restrict__ B, int ldb, long sB,
           void* __restrict__ Out, int ldc, long sC,
           const float* __restrict__ aux, int Kdim,
           float* __restrict__ f0, float* __restrict__ f1)
{
  __shared__ f16 lA[4][128*32];    // 32 KB
  __shared__ f16 lB[4][128*32];    // 32 KB
  __shared__ float smx[4][4][16], szx[4][4][16];  // stats scratch (OMODE 1)

  // XCD-aware tile swizzle within each z-plane (requires nwg % 8 == 0; all
  // our grids satisfy it). Consecutive logical tiles share the B-panel and
  // land on the SAME XCD -> panel reads L2-hit.
  const int nx = gridDim.x, nwg = nx * gridDim.y, cpx = nwg >> 3;
  int id = blockIdx.x + nx * blockIdx.y;
  id = (id & 7) * cpx + (id >> 3);
  const int bx = id % nx, by = id / nx;

  const int b = blockIdx.z;
  const f16* A_ = A + (size_t)b * sA;
  const f16* B_ = B + (size_t)b * sB;
  const int m0 = bx * 128, n0 = by * 128;
  const int tid = threadIdx.x, lane = tid & 63, wave = tid >> 6;
  const int wm = wave >> 1, wn = wave & 1;

  // staging: 512 x 16B chunks per 128x32 tile; chunk c -> row=c>>2, dest slot
  // c&3 (LDS stays linear), SOURCE slot = (c&3) ^ GSWZ(row)  [involution]
  const int c0 = tid, c1 = 256 + tid;
  const int r0 = c0 >> 2, s0 = (c0 & 3) ^ GSWZ(r0);
  const int r1 = c1 >> 2, s1 = (c1 & 3) ^ GSWZ(r1);
  const size_t ga0 = (size_t)(m0 + r0) * lda + s0 * 8;
  const size_t ga1 = (size_t)(m0 + r1) * lda + s1 * 8;
  const size_t gb0 = (size_t)(n0 + r0) * ldb + s0 * 8;
  const size_t gb1 = (size_t)(n0 + r1) * ldb + s1 * 8;

  f32x4 acc[4][4] = {};
  const int NT = Kdim >> 5;

  auto STAGE = [&](int u, int kt){
    gload16(A_ + ga0 + kt, &lA[u][c0*8]);
    gload16(A_ + ga1 + kt, &lA[u][c1*8]);
    gload16(B_ + gb0 + kt, &lB[u][c0*8]);
    gload16(B_ + gb1 + kt, &lB[u][c1*8]);
  };
  STAGE(0, 0); STAGE(1, 32); STAGE(2, 64);   // 12 loads/wave in flight

  // frag reads (swizzled): row = base + frow, slot = (lane>>4) ^ GSWZ(frow)
  const int frow = lane & 15;
  const int rsl = (((lane >> 4) ^ GSWZ(frow)) & 3) * 8;
  const int offA = (wm*64 + frow)*32 + rsl;
  const int offB = (wn*64 + frow)*32 + rsl;

  for (int t = 0; t < NT; ++t){
    const int u = t & 3;
    __builtin_amdgcn_s_barrier();            // all waves done reading buf[(t-1)&3]
    __builtin_amdgcn_sched_barrier(0);
    if (t + 3 < NT) STAGE((t + 3) & 3, (t + 3) * 32);
    const int rem = NT - 1 - t;
    if (rem >= 3)      asm volatile("s_waitcnt vmcnt(12)" ::: "memory");
    else if (rem == 2) asm volatile("s_waitcnt vmcnt(8)"  ::: "memory");
    else if (rem == 1) asm volatile("s_waitcnt vmcnt(4)"  ::: "memory");
    else               asm volatile("s_waitcnt vmcnt(0)"  ::: "memory");
    __builtin_amdgcn_s_barrier();            // tile-t loads landed for all waves
    __builtin_amdgcn_sched_barrier(0);

    const f16* tA = &lA[u][0] + offA;
    const f16* tB = &lB[u][0] + offB;
    half8 af[4], bf[4];
#pragma unroll
    for (int i = 0; i < 4; ++i) af[i] = *(const half8*)(tA + i*512);
#pragma unroll
    for (int j = 0; j < 4; ++j) bf[j] = *(const half8*)(tB + j*512);
    __builtin_amdgcn_s_setprio(1);
#pragma unroll
    for (int i = 0; i < 4; ++i)
#pragma unroll
      for (int j = 0; j < 4; ++j)
        acc[i][j] = __builtin_amdgcn_mfma_f32_16x16x32_f16(af[i], bf[j], acc[i][j], 0,0,0);
    __builtin_amdgcn_s_setprio(0);
  }

  // epilogue; C/D layout: col = lane&15, row = (lane>>4)*4 + r  [m89 verified]
#pragma unroll
  for (int i = 0; i < 4; ++i)
#pragma unroll
    for (int j = 0; j < 4; ++j){
      const int gc = n0 + wn*64 + j*16 + frow;
      float bias_v = 0.f;
      if constexpr (OMODE == 0) bias_v = aux[b*DD + gc];
#pragma unroll
      for (int r = 0; r < 4; ++r){
        const int gr = m0 + wm*64 + i*16 + (lane >> 4)*4 + r;
        float v = acc[i][j][r];
        if constexpr (OMODE == 0){
          ((f16*)Out)[(size_t)b*sC + (size_t)gr*ldc + gc] = (f16)(v + bias_v);
        } else if constexpr (OMODE == 1){
          ((float*)Out)[(size_t)b*sC + (size_t)gr*ldc + gc] = v;
        } else {
          size_t o = (size_t)b*sC + (size_t)gr*ldc + gc;
          ((float*)Out)[o] = v + aux[o];   // aux = residual x, same flat layout
        }
      }
    }

  if constexpr (OMODE == 1){
    // fused column-stats partial over this block's 128 rows, per column
    float pmj[4], pzj[4];
#pragma unroll
    for (int j = 0; j < 4; ++j){
      float mx = acc[0][j][0];
#pragma unroll
      for (int i = 0; i < 4; ++i)
#pragma unroll
        for (int r = 0; r < 4; ++r) mx = fmaxf(mx, acc[i][j][r]);
      float zz = 0.f;
#pragma unroll
      for (int i = 0; i < 4; ++i)
#pragma unroll
        for (int r = 0; r < 4; ++r) zz += __expf(acc[i][j][r] - mx);
      // butterfly over lane bits 4,5 (the 4 row-groups share a column)
#pragma unroll
      for (int off = 16; off < 64; off <<= 1){
        float mo = __shfl_xor(mx, off, 64);
        float zo = __shfl_xor(zz, off, 64);
        float M = fmaxf(mx, mo);
        zz = zz*__expf(mx - M) + zo*__expf(mo - M);
        mx = M;
      }
      pmj[j] = mx; pzj[j] = zz;
    }
    if (lane < 16){
#pragma unroll
      for (int j = 0; j < 4; ++j){ smx[wave][j][lane] = pmj[j]; szx[wave][j][lane] = pzj[j]; }
    }
    __syncthreads();
    if (wm == 0 && lane < 16){     // waves 0,1 merge partner waves 2,3 (same wn)
#pragma unroll
      for (int j = 0; j < 4; ++j){
        float m1 = smx[wave + 2][j][lane], z1 = szx[wave + 2][j][lane];
        float M = fmaxf(pmj[j], m1);
        float Z = pzj[j]*__expf(pmj[j] - M) + z1*__expf(m1 - M);
        const int gc = n0 + wn*64 + j*16 + lane;
        size_t o = ((size_t)b * NQC + bx) * TT + gc;
        f0[o] = M; f1[o] = Z;
      }
    }
  }
}

// ------- merge NQC row-block partials per column -> mcol, zinv -------
__global__ __launch_bounds__(256)
void statsB_kernel(const float* __restrict__ pm, const float* __restrict__ pz,
                   float* __restrict__ mcol, float* __restrict__ zinv){
  const int b = blockIdx.y;
  const int t = blockIdx.x * 256 + threadIdx.x;
  float M = -3.0e38f;
#pragma unroll
  for (int k = 0; k < NQC; ++k)
    M = fmaxf(M, pm[((size_t)b * NQC + k) * TT + t]);
  float Z = 0.f;
#pragma unroll
  for (int k = 0; k < NQC; ++k){
    size_t o = ((size_t)b * NQC + k) * TT + t;
    Z += pz[o] * __expf(pm[o] - M);
  }
  mcol[b*TT + t] = M;
  zinv[b*TT + t] = 1.f / (Z * 27.712812921102035f);  // 1/(Z*sqrt(768))
}

// ---------------- P = exp(S - m_t) * zinv_t -> f16 ----------------
__global__ __launch_bounds__(256)
void pexp_kernel(const float* __restrict__ S, const float* __restrict__ mcol,
                 const float* __restrict__ zinv, f16* __restrict__ P, int G){
  const int n4 = G * (TT*TT/4);
  const int stride = gridDim.x * 256;
  for (int i = blockIdx.x*256 + threadIdx.x; i < n4; i += stride){
    float4 s4 = ((const float4*)S)[i];
    int t   = (i*4) & (TT - 1);
    int row = (int)(((size_t)i * 4) >> 11);   // row within chunk
    int b   = row >> 11;                      // local batch
    int bt = b * TT + t;
    float4 m4 = *(const float4*)&mcol[bt];
    float4 z4 = *(const float4*)&zinv[bt];
    half4 o;
    o[0] = (f16)(__expf(s4.x - m4.x) * z4.x);
    o[1] = (f16)(__expf(s4.y - m4.y) * z4.y);
    o[2] = (f16)(__expf(s4.z - m4.z) * z4.z);
    o[3] = (f16)(__expf(s4.w - m4.w) * z4.w);
    ((half4*)P)[i] = o;
  }
}

// ---------------- V [t,v] -> Vt [v,t] (per local batch z) ----------------
__global__ __launch_bounds__(256)
void transp_kernel(const u16* __restrict__ V, u16* __restrict__ Vt){
  const int b = blockIdx.z;
  const int t0 = blockIdx.x * 64, v0 = blockIdx.y * 64;
  const u16* Vb = V + (size_t)b * TT * DD;
  u16* Vtb = Vt + (size_t)b * DD * TT;
  __shared__ u16 tile[64][66];
  const int tid = threadIdx.x;
#pragma unroll
  for (int i = 0; i < 4; ++i){
    int c = i*256 + tid;
    int r = c >> 4, c4 = (c & 15) * 4;
    ushort4 u = *(const ushort4*)&Vb[(size_t)(t0 + r) * DD + v0 + c4];
    tile[r][c4+0] = u.x; tile[r][c4+1] = u.y; tile[r][c4+2] = u.z; tile[r][c4+3] = u.w;
  }
  __syncthreads();
#pragma unroll
  for (int i = 0; i < 4; ++i){
    int c = i*256 + tid;
    int vr = c >> 4, t4 = (c & 15) * 4;
    ushort4 u;
    u.x = tile[t4+0][vr]; u.y = tile[t4+1][vr]; u.z = tile[t4+2][vr]; u.w = tile[t4+3][vr];
    *(ushort4*)&Vtb[(size_t)(v0 + vr) * TT + t0 + t4] = u;
  }
}

// ---------------- LayerNorm (in-place on d_out), one row per block ----------------
__global__ __launch_bounds__(256)
void ln_kernel(float* __restrict__ y, const float* __restrict__ gamma,
               const float* __restrict__ beta){
  const int row = blockIdx.x;
  float* p = y + (size_t)row * DD;
  const int tid = threadIdx.x;
  float v[3]; float s = 0.f, sq = 0.f;
#pragma unroll
  for (int k = 0; k < 3; ++k){
    v[k] = p[tid + k*256];
    s += v[k]; sq += v[k]*v[k];
  }
#pragma unroll
  for (int off = 32; off > 0; off >>= 1){
    s  += __shfl_down(s,  off, 64);
    sq += __shfl_down(sq, off, 64);
  }
  __shared__ float red[8];
  const int lane = tid & 63, w = tid >> 6;
  if (lane == 0){ red[w] = s; red[4+w] = sq; }
  __syncthreads();
  if (tid == 0){
    red[0] = red[0]+red[1]+red[2]+red[3];
    red[4] = red[4]+red[5]+red[6]+red[7];
  }
  __syncthreads();
  const float mu  = red[0] * (1.f/DD);
  const float var = red[4] * (1.f/DD) - mu*mu;
  const float rs  = rsqrtf(var + 1e-5f);
#pragma unroll
  for (int k = 0; k < 3; ++k){
    int c = tid + k*256;
    p[c] = (v[k] - mu) * rs * gamma[c] + beta[c];
  }
}

extern "C" void kernel_launch(void* const* d_in, const int* in_sizes, int n_in,
                              void* d_out, int out_size, void* d_ws, size_t ws_size,
                              hipStream_t stream)
{
  // setup_inputs order: x, Wk, bk, Wq, bq, Wv, bv, gamma, beta
  const float* x    = (const float*)d_in[0];
  const float* Wk   = (const float*)d_in[1];
  const float* bk   = (const float*)d_in[2];
  const float* Wq   = (const float*)d_in[3];
  const float* bq   = (const float*)d_in[4];
  const float* Wv   = (const float*)d_in[5];
  const float* bv   = (const float*)d_in[6];
  const float* gamma= (const float*)d_in[7];
  const float* beta = (const float*)d_in[8];
  float* out = (float*)d_out;

  const size_t PW   = (size_t)DD*DD*2;   // f16 weight plane
  const size_t PB   = (size_t)TT*DD*2;   // f16 activation plane per batch
  const size_t SB   = (size_t)TT*TT*4;   // f32 S per batch
  const size_t PPc  = (size_t)TT*TT*2;   // f16 P per batch
  const size_t T4   = (size_t)TT*4;
  auto al = [](size_t n){ return (n + 255) & ~(size_t)255; };

  // full-PV layout: Vt + P are full-batch; X/Q/K/V/S chunked by G
  auto needFull = [&](int G)->size_t{
    return al(3*PW) + al(3*DD*4) + al((size_t)BB*PB) + al((size_t)BB*PPc)
         + 4*al((size_t)G*PB) + al((size_t)G*SB)
         + 2*al((size_t)G*NQC*T4) + 2*al((size_t)G*T4);
  };
  // fallback: everything chunked (PV per chunk)
  auto needFb = [&](int G)->size_t{
    return al(3*PW) + al(3*DD*4) + al((size_t)G*PB) + al((size_t)G*PPc)
         + 4*al((size_t)G*PB) + al((size_t)G*SB)
         + 2*al((size_t)G*NQC*T4) + 2*al((size_t)G*T4);
  };

  int G = 0; bool fullPV = false;
  for (int g : {4, 2, 1}) if (needFull(g) <= ws_size){ G = g; fullPV = true; break; }
  if (!fullPV) for (int g : {4, 2, 1}) if (needFb(g) <= ws_size){ G = g; break; }
  if (G == 0) return;

  char* p = (char*)d_ws;
  auto alloc = [&](size_t n)->char*{ char* r = p; p += (n + 255) & ~(size_t)255; return r; };
  f16*   Wf    = (f16*)alloc(3*PW);            // [Wq;Wk;Wv] stacked
  float* biasf = (float*)alloc(3*DD*4);        // [bq;bk;bv] stacked
  f16*   Vt    = (f16*)alloc((fullPV ? (size_t)BB : (size_t)G) * PB);
  f16*   P     = (f16*)alloc((fullPV ? (size_t)BB : (size_t)G) * PPc);
  f16*   Xc    = (f16*)alloc((size_t)G * PB);
  f16*   QKVc  = (f16*)alloc(3*(size_t)G * PB);     // Q,K,V contiguous chunk planes
  float* Sc    = (float*)alloc((size_t)G * SB);
  float* pm    = (float*)alloc((size_t)G * NQC * T4);
  float* pz    = (float*)alloc((size_t)G * NQC * T4);
  float* mcol  = (float*)alloc((size_t)G * T4);
  float* zinv  = (float*)alloc((size_t)G * T4);
  f16* Qc = QKVc, *Kc = QKVc + (size_t)G*TT*DD, *Vc = QKVc + 2*(size_t)G*TT*DD;

  tofp16_kernel<<<288, 256, 0, stream>>>(Wq, Wf,             DD*DD/4);
  tofp16_kernel<<<288, 256, 0, stream>>>(Wk, Wf +   DD*DD,   DD*DD/4);
  tofp16_kernel<<<288, 256, 0, stream>>>(Wv, Wf + 2*DD*DD,   DD*DD/4);
  hipMemcpyAsync(biasf,        bq, DD*4, hipMemcpyDeviceToDevice, stream);
  hipMemcpyAsync(biasf +   DD, bk, DD*4, hipMemcpyDeviceToDevice, stream);
  hipMemcpyAsync(biasf + 2*DD, bv, DD*4, hipMemcpyDeviceToDevice, stream);

  const int nRows = G * TT;
  for (int b0 = 0; b0 < BB; b0 += G){
    tofp16_kernel<<<2048, 256, 0, stream>>>(x + (size_t)b0*TT*DD, Xc, nRows*DD/4);

    // merged Q,K,V projections: z = proj index
    dim3 gp(nRows/128, DD/128, 3);
    gemmk<0><<<gp, 256, 0, stream>>>(Xc, DD, 0, Wf, DD, (long)DD*DD,
                                     QKVc, DD, (long)G*TT*DD, biasf, DD,
                                     nullptr, nullptr);

    transp_kernel<<<dim3(TT/64, DD/64, G), 256, 0, stream>>>(
        (const u16*)Vc, (u16*)(Vt + (fullPV ? (size_t)b0*DD*TT : 0)));

    // S = Q K^T (f32) + fused column-stats partials
    dim3 gs(TT/128, TT/128, G);
    gemmk<1><<<gs, 256, 0, stream>>>(Qc, DD, (long)TT*DD, Kc, DD, (long)TT*DD,
                                     Sc, TT, (long)TT*TT, nullptr, DD, pm, pz);

    statsB_kernel<<<dim3(TT/256, G), 256, 0, stream>>>(pm, pz, mcol, zinv);
    pexp_kernel<<<2048, 256, 0, stream>>>(Sc, mcol, zinv,
                                          P + (fullPV ? (size_t)b0*TT*TT : 0), G);

    if (!fullPV){
      dim3 gpv(TT/128, DD/128, G);
      gemmk<2><<<gpv, 256, 0, stream>>>(P, TT, (long)TT*TT, Vt, TT, (long)DD*TT,
                                        out + (size_t)b0*TT*DD, DD, (long)TT*DD,
                                        x + (size_t)b0*TT*DD, TT, nullptr, nullptr);
    }
  }

  if (fullPV){
    dim3 gpv(TT/128, DD/128, BB);   // 1536 blocks, 2 blocks/CU resident
    gemmk<2><<<gpv, 256, 0, stream>>>(P, TT, (long)TT*TT, Vt, TT, (long)DD*TT,
                                      out, DD, (long)TT*DD, x, TT, nullptr, nullptr);
  }

  ln_kernel<<<BT, 256, 0, stream>>>(out, gamma, beta);
}

// Round 8
// 696.348 us; speedup vs baseline: 1.3393x; 1.1689x over previous
//
#include <hip/hip_runtime.h>
#include <hip/hip_fp16.h>

// Problem constants (reference: B=16, T=2048, D=768)
#define DD 768
#define BB 16
#define TT 2048
#define BT (BB*TT)   // 32768
#define NQC 16       // 128-row blocks per batch for column-softmax stats

using u16 = unsigned short;
using f16 = _Float16;
typedef __attribute__((ext_vector_type(8))) f16 half8;   // MFMA A/B frag (4 VGPR)
typedef __attribute__((ext_vector_type(4))) f16 half4;   // 8B
typedef __attribute__((ext_vector_type(4))) float f32x4; // MFMA C/D frag

// XOR involution on 16B slots within a row: spreads K-slots across banks
#define GSWZ(r) ((((r) & 3)) ^ (((r) >> 2) & 3))

typedef const __attribute__((address_space(1))) unsigned int* gas1;
typedef __attribute__((address_space(3))) unsigned int* las3;
__device__ __forceinline__ void gload16(const void* g, void* l){
  __builtin_amdgcn_global_load_lds((gas1)g, (las3)l, 16, 0, 0);
}

// ---------------- fp32 -> fp16 ----------------
__global__ __launch_bounds__(256)
void tofp16_kernel(const float* __restrict__ src, f16* __restrict__ dst, int n4){
  const int stride = gridDim.x * 256;
  for (int i = blockIdx.x*256 + threadIdx.x; i < n4; i += stride){
    float4 v = ((const float4*)src)[i];
    half4 h; h[0]=(f16)v.x; h[1]=(f16)v.y; h[2]=(f16)v.z; h[3]=(f16)v.w;
    ((half4*)dst)[i] = h;
  }
}

// =================================================================
// 128x128 NT GEMM, 256 threads (4 waves 2x2), BK=32, 4-deep LDS
// pipeline, counted vmcnt, 2 blocks/CU, XCD swizzle with A-panel
// reuse (by-fastest within each XCD's contiguous work range).
// OMODE 0: merged QKV proj. z=proj: B=W[z], out f16 = acc + bias[z]
// OMODE 1: S->P'' = exp(S - M_blk) f16 out; pm/pz partials (f0,f1)
// OMODE 2: PV: z=batch, out f16 = acc (no residual)
// =================================================================
template<int OMODE>
__global__ __launch_bounds__(256, 2)
void gemmk(const f16* __restrict__ A, int lda, long sA,
           const f16* __restrict__ B, int ldb, long sB,
           void* __restrict__ Out, int ldc, long sC,
           const float* __restrict__ aux, int Kdim,
           float* __restrict__ f0, float* __restrict__ f1)
{
  __shared__ f16 lA[4][128*32];    // 32 KB
  __shared__ f16 lB[4][128*32];    // 32 KB
  __shared__ float smx[4][4][16], szx[4][4][16];

  // XCD swizzle (nwg % 8 == 0 on all our grids). XCD k gets a contiguous
  // work range; works decoded by-FASTEST so consecutive works on one XCD
  // share the A-panel (the 6-16x re-read operand) -> L2 hits.
  const int nx = gridDim.x, ny = gridDim.y, nwg = nx * ny, cpx = nwg >> 3;
  int h = blockIdx.x + nx * blockIdx.y;
  h = (h & 7) * cpx + (h >> 3);
  const int bx = h / ny, by = h % ny;

  const int b = blockIdx.z;
  const f16* A_ = A + (size_t)b * sA;
  const f16* B_ = B + (size_t)b * sB;
  const int m0 = bx * 128, n0 = by * 128;
  const int tid = threadIdx.x, lane = tid & 63, wave = tid >> 6;
  const int wm = wave >> 1, wn = wave & 1;

  // staging: chunk c -> row=c>>2, dest slot c&3 (LDS linear),
  // SOURCE slot = (c&3) ^ GSWZ(row)  [involution]
  const int c0 = tid, c1 = 256 + tid;
  const int r0 = c0 >> 2, s0 = (c0 & 3) ^ GSWZ(r0);
  const int r1 = c1 >> 2, s1 = (c1 & 3) ^ GSWZ(r1);
  const size_t ga0 = (size_t)(m0 + r0) * lda + s0 * 8;
  const size_t ga1 = (size_t)(m0 + r1) * lda + s1 * 8;
  const size_t gb0 = (size_t)(n0 + r0) * ldb + s0 * 8;
  const size_t gb1 = (size_t)(n0 + r1) * ldb + s1 * 8;

  f32x4 acc[4][4] = {};
  const int NT = Kdim >> 5;

  auto STAGE = [&](int u, int kt){
    gload16(A_ + ga0 + kt, &lA[u][c0*8]);
    gload16(A_ + ga1 + kt, &lA[u][c1*8]);
    gload16(B_ + gb0 + kt, &lB[u][c0*8]);
    gload16(B_ + gb1 + kt, &lB[u][c1*8]);
  };
  STAGE(0, 0); STAGE(1, 32); STAGE(2, 64);   // 12 loads/wave in flight

  const int frow = lane & 15;
  const int rsl = (((lane >> 4) ^ GSWZ(frow)) & 3) * 8;
  const int offA = (wm*64 + frow)*32 + rsl;
  const int offB = (wn*64 + frow)*32 + rsl;

  for (int t = 0; t < NT; ++t){
    const int u = t & 3;
    __builtin_amdgcn_s_barrier();            // readers of buf[(t+3)&3] done
    __builtin_amdgcn_sched_barrier(0);
    if (t + 3 < NT) STAGE((t + 3) & 3, (t + 3) * 32);
    const int rem = NT - 1 - t;
    if (rem >= 3)      asm volatile("s_waitcnt vmcnt(12)" ::: "memory");
    else if (rem == 2) asm volatile("s_waitcnt vmcnt(8)"  ::: "memory");
    else if (rem == 1) asm volatile("s_waitcnt vmcnt(4)"  ::: "memory");
    else               asm volatile("s_waitcnt vmcnt(0)"  ::: "memory");
    __builtin_amdgcn_s_barrier();            // tile-t landed for all waves
    __builtin_amdgcn_sched_barrier(0);

    const f16* tA = &lA[u][0] + offA;
    const f16* tB = &lB[u][0] + offB;
    half8 af[4], bf[4];
#pragma unroll
    for (int i = 0; i < 4; ++i) af[i] = *(const half8*)(tA + i*512);
#pragma unroll
    for (int j = 0; j < 4; ++j) bf[j] = *(const half8*)(tB + j*512);
    __builtin_amdgcn_s_setprio(1);
#pragma unroll
    for (int i = 0; i < 4; ++i)
#pragma unroll
      for (int j = 0; j < 4; ++j)
        acc[i][j] = __builtin_amdgcn_mfma_f32_16x16x32_f16(af[i], bf[j], acc[i][j], 0,0,0);
    __builtin_amdgcn_s_setprio(0);
  }

  // epilogue; C/D layout: col = lane&15, row = (lane>>4)*4 + r  [m89 verified]
  const int kq4 = (lane >> 4) * 4;
  if constexpr (OMODE == 0 || OMODE == 2){
    f16* O = (f16*)Out + (size_t)b * sC;
#pragma unroll
    for (int j = 0; j < 4; ++j){
      const int gc = n0 + wn*64 + j*16 + frow;
      float bias_v = 0.f;
      if constexpr (OMODE == 0) bias_v = aux[b*DD + gc];
#pragma unroll
      for (int i = 0; i < 4; ++i)
#pragma unroll
        for (int r = 0; r < 4; ++r){
          const int gr = m0 + wm*64 + i*16 + kq4 + r;
          O[(size_t)gr*ldc + gc] = (f16)(acc[i][j][r] + bias_v);
        }
    }
  } else {
    // S -> P'' = exp(S - M_blk) f16, + per-(rowblock,column) partials
    f16* O = (f16*)Out + (size_t)b * sC;
    float Mb[4], Zb[4];
#pragma unroll
    for (int j = 0; j < 4; ++j){
      float mx = acc[0][j][0];
#pragma unroll
      for (int i = 0; i < 4; ++i)
#pragma unroll
        for (int r = 0; r < 4; ++r) mx = fmaxf(mx, acc[i][j][r]);
      mx = fmaxf(mx, __shfl_xor(mx, 16, 64));
      mx = fmaxf(mx, __shfl_xor(mx, 32, 64));
      if (lane < 16) smx[wave][j][lane] = mx;
      Mb[j] = mx;
    }
    __syncthreads();
#pragma unroll
    for (int j = 0; j < 4; ++j)
      Mb[j] = fmaxf(Mb[j], smx[wave ^ 2][j][frow]);   // block-level column max
#pragma unroll
    for (int j = 0; j < 4; ++j){
      const int gc = n0 + wn*64 + j*16 + frow;
      float zz = 0.f;
#pragma unroll
      for (int i = 0; i < 4; ++i)
#pragma unroll
        for (int r = 0; r < 4; ++r){
          const int gr = m0 + wm*64 + i*16 + kq4 + r;
          float e = __expf(acc[i][j][r] - Mb[j]);
          zz += e;
          O[(size_t)gr*ldc + gc] = (f16)e;
        }
      zz += __shfl_xor(zz, 16, 64);
      zz += __shfl_xor(zz, 32, 64);
      if (lane < 16) szx[wave][j][lane] = zz;
      Zb[j] = zz;
    }
    __syncthreads();
    if (wm == 0 && lane < 16){
#pragma unroll
      for (int j = 0; j < 4; ++j){
        const int gc = n0 + wn*64 + j*16 + lane;
        size_t o = ((size_t)b * NQC + bx) * TT + gc;
        f0[o] = Mb[j];
        f1[o] = Zb[j] + szx[wave + 2][j][lane];
      }
    }
  }
}

// ------- merge NQC partials; emit c[rb][t] = exp(pm - M) * zinv -------
__global__ __launch_bounds__(256)
void statsB_kernel(const float* __restrict__ pm, const float* __restrict__ pz,
                   float* __restrict__ c){
  const int b = blockIdx.y;
  const int t = blockIdx.x * 256 + threadIdx.x;
  float am[NQC], az[NQC];
#pragma unroll
  for (int k = 0; k < NQC; ++k){
    size_t o = ((size_t)b * NQC + k) * TT + t;
    am[k] = pm[o]; az[k] = pz[o];
  }
  float M = am[0];
#pragma unroll
  for (int k = 1; k < NQC; ++k) M = fmaxf(M, am[k]);
  float Z = 0.f;
#pragma unroll
  for (int k = 0; k < NQC; ++k) Z += az[k] * __expf(am[k] - M);
  const float zi = 1.f / (Z * 27.712812921102035f);  // 1/(Z*sqrt(768))
#pragma unroll
  for (int k = 0; k < NQC; ++k)
    c[((size_t)b * NQC + k) * TT + t] = __expf(am[k] - M) * zi;
}

// ------- in-place P = P'' * c[b][rb][t]  (full batch) -------
__global__ __launch_bounds__(256)
void fixup_kernel(half8* __restrict__ P, const float* __restrict__ c){
  const long n8 = (long)BB * TT * TT / 8;
  const long stride = (long)gridDim.x * 256;
  for (long i = (long)blockIdx.x*256 + threadIdx.x; i < n8; i += stride){
    const long e = i * 8;
    const int t0 = (int)(e & (TT - 1));
    const long qg = e >> 11;
    const int bq = (int)(qg >> 11);
    const int rb = ((int)(qg & (TT - 1))) >> 7;
    const float* cp = &c[((size_t)(bq * NQC + rb)) * TT + t0];
    half8 p = P[i], o;
#pragma unroll
    for (int k = 0; k < 8; ++k) o[k] = (f16)((float)p[k] * cp[k]);
    P[i] = o;
  }
}

// ---------------- V [t,v] -> Vt [v,t] (per local batch z) ----------------
__global__ __launch_bounds__(256)
void transp_kernel(const u16* __restrict__ V, u16* __restrict__ Vt){
  const int b = blockIdx.z;
  const int t0 = blockIdx.x * 64, v0 = blockIdx.y * 64;
  const u16* Vb = V + (size_t)b * TT * DD;
  u16* Vtb = Vt + (size_t)b * DD * TT;
  __shared__ u16 tile[64][66];
  const int tid = threadIdx.x;
#pragma unroll
  for (int i = 0; i < 4; ++i){
    int cI = i*256 + tid;
    int r = cI >> 4, c4 = (cI & 15) * 4;
    ushort4 u = *(const ushort4*)&Vb[(size_t)(t0 + r) * DD + v0 + c4];
    tile[r][c4+0] = u.x; tile[r][c4+1] = u.y; tile[r][c4+2] = u.z; tile[r][c4+3] = u.w;
  }
  __syncthreads();
#pragma unroll
  for (int i = 0; i < 4; ++i){
    int cI = i*256 + tid;
    int vr = cI >> 4, t4 = (cI & 15) * 4;
    ushort4 u;
    u.x = tile[t4+0][vr]; u.y = tile[t4+1][vr]; u.z = tile[t4+2][vr]; u.w = tile[t4+3][vr];
    *(ushort4*)&Vtb[(size_t)(v0 + vr) * TT + t0 + t4] = u;
  }
}

// ------- residual + LayerNorm: out = LN(applied_f16 + x) -------
__global__ __launch_bounds__(192)
void ln2_kernel(const half4* __restrict__ applied, const float4* __restrict__ x,
                const float4* __restrict__ gamma4, const float4* __restrict__ beta4,
                float4* __restrict__ out){
  const size_t base = (size_t)blockIdx.x * (DD/4);
  const int cc = threadIdx.x;          // 0..191
  half4 a4 = applied[base + cc];
  float4 x4 = x[base + cc];
  float y0 = (float)a4[0] + x4.x;
  float y1 = (float)a4[1] + x4.y;
  float y2 = (float)a4[2] + x4.z;
  float y3 = (float)a4[3] + x4.w;
  float s = y0+y1+y2+y3;
  float sq = y0*y0+y1*y1+y2*y2+y3*y3;
#pragma unroll
  for (int off = 32; off > 0; off >>= 1){
    s  += __shfl_down(s,  off, 64);
    sq += __shfl_down(sq, off, 64);
  }
  __shared__ float rs_[3], rq_[3];
  const int lane = threadIdx.x & 63, w = threadIdx.x >> 6;
  if (lane == 0){ rs_[w] = s; rq_[w] = sq; }
  __syncthreads();
  const float S_ = rs_[0]+rs_[1]+rs_[2];
  const float Q_ = rq_[0]+rq_[1]+rq_[2];
  const float mu  = S_ * (1.f/DD);
  const float var = Q_ * (1.f/DD) - mu*mu;
  const float rstd = rsqrtf(var + 1e-5f);
  float4 g = gamma4[cc], be = beta4[cc], o;
  o.x = (y0 - mu)*rstd*g.x + be.x;
  o.y = (y1 - mu)*rstd*g.y + be.y;
  o.z = (y2 - mu)*rstd*g.z + be.z;
  o.w = (y3 - mu)*rstd*g.w + be.w;
  out[base + cc] = o;
}

extern "C" void kernel_launch(void* const* d_in, const int* in_sizes, int n_in,
                              void* d_out, int out_size, void* d_ws, size_t ws_size,
                              hipStream_t stream)
{
  const float* x    = (const float*)d_in[0];
  const float* Wk   = (const float*)d_in[1];
  const float* bk   = (const float*)d_in[2];
  const float* Wq   = (const float*)d_in[3];
  const float* bq   = (const float*)d_in[4];
  const float* Wv   = (const float*)d_in[5];
  const float* bv   = (const float*)d_in[6];
  const float* gamma= (const float*)d_in[7];
  const float* beta = (const float*)d_in[8];
  float* out = (float*)d_out;

  const size_t PW = (size_t)DD*DD*2;    // f16 weight plane
  const size_t PB = (size_t)TT*DD*2;    // f16 activation plane per batch
  const size_t T4 = (size_t)TT*4;
  auto al = [](size_t n){ return (n + 255) & ~(size_t)255; };

  auto need = [&](int G)->size_t{
    size_t t = al(3*PW) + al(3*DD*4) + al((size_t)BB*PB) + al((size_t)BB*TT*TT*2)
             + al((size_t)G*PB) + al(3*(size_t)G*PB)
             + 2*al((size_t)G*NQC*T4) + al((size_t)BB*NQC*T4);
    if (4*(size_t)G*PB < (size_t)BB*PB) t += al((size_t)BB*PB);  // applied alias shortfall
    return t;
  };

  int G = 0;
  for (int g : {8, 4, 2, 1}) if (need(g) <= ws_size){ G = g; break; }
  if (G == 0) return;

  char* p = (char*)d_ws;
  auto alloc = [&](size_t n)->char*{ char* r = p; p += (n + 255) & ~(size_t)255; return r; };
  f16*   Wf    = (f16*)alloc(3*PW);            // [Wq;Wk;Wv]
  float* biasf = (float*)alloc(3*DD*4);        // [bq;bk;bv]
  f16*   Vt    = (f16*)alloc((size_t)BB*PB);
  f16*   P16   = (f16*)alloc((size_t)BB*TT*TT*2);
  f16*   Xc    = (f16*)alloc((size_t)G*PB);
  f16*   QKVc  = (f16*)alloc(3*(size_t)G*PB);
  float* pm    = (float*)alloc((size_t)G*NQC*T4);
  float* pz    = (float*)alloc((size_t)G*NQC*T4);
  float* cbuf  = (float*)alloc((size_t)BB*NQC*T4);
  f16* applied = (4*(size_t)G*PB >= (size_t)BB*PB) ? Xc
               : (f16*)alloc((size_t)BB*PB);    // aliases dead Xc+QKVc when G>=4
  f16* Qc = QKVc, *Kc = QKVc + (size_t)G*TT*DD, *Vc = QKVc + 2*(size_t)G*TT*DD;

  tofp16_kernel<<<288, 256, 0, stream>>>(Wq, Wf,             DD*DD/4);
  tofp16_kernel<<<288, 256, 0, stream>>>(Wk, Wf +   DD*DD,   DD*DD/4);
  tofp16_kernel<<<288, 256, 0, stream>>>(Wv, Wf + 2*DD*DD,   DD*DD/4);
  hipMemcpyAsync(biasf,        bq, DD*4, hipMemcpyDeviceToDevice, stream);
  hipMemcpyAsync(biasf +   DD, bk, DD*4, hipMemcpyDeviceToDevice, stream);
  hipMemcpyAsync(biasf + 2*DD, bv, DD*4, hipMemcpyDeviceToDevice, stream);

  const int nRows = G * TT;
  for (int b0 = 0; b0 < BB; b0 += G){
    tofp16_kernel<<<2048, 256, 0, stream>>>(x + (size_t)b0*TT*DD, Xc, nRows*DD/4);

    dim3 gp(nRows/128, DD/128, 3);
    gemmk<0><<<gp, 256, 0, stream>>>(Xc, DD, 0, Wf, DD, (long)DD*DD,
                                     QKVc, DD, (long)G*TT*DD, biasf, DD,
                                     nullptr, nullptr);

    transp_kernel<<<dim3(TT/64, DD/64, G), 256, 0, stream>>>(
        (const u16*)Vc, (u16*)(Vt + (size_t)b0*DD*TT));

    // S = Q K^T -> P'' f16 directly into P16, + stats partials
    dim3 gs(TT/128, TT/128, G);
    gemmk<1><<<gs, 256, 0, stream>>>(Qc, DD, (long)TT*DD, Kc, DD, (long)TT*DD,
                                     P16 + (size_t)b0*TT*TT, TT, (long)TT*TT,
                                     nullptr, DD, pm, pz);

    statsB_kernel<<<dim3(TT/256, G), 256, 0, stream>>>(
        pm, pz, cbuf + (size_t)b0*NQC*TT);
  }

  fixup_kernel<<<2048, 256, 0, stream>>>((half8*)P16, cbuf);

  // PV over all batches -> applied f16
  dim3 gpv(TT/128, DD/128, BB);
  gemmk<2><<<gpv, 256, 0, stream>>>(P16, TT, (long)TT*TT, Vt, TT, (long)DD*TT,
                                    applied, DD, (long)TT*DD, nullptr, TT,
                                    nullptr, nullptr);

  ln2_kernel<<<BT, 192, 0, stream>>>((const half4*)applied, (const float4*)x,
                                     (const float4*)gamma, (const float4*)beta,
                                     (float4*)out);
}

// Round 9
// 580.660 us; speedup vs baseline: 1.6062x; 1.1992x over previous
//
#include <hip/hip_runtime.h>
#include <hip/hip_fp16.h>
#include <string.h>

// Problem constants (reference: B=16, T=2048, D=768)
#define DD 768
#define BB 16
#define TT 2048
#define BT (BB*TT)   // 32768
#define NQC 16       // 128-row blocks per batch for column-softmax stats

using u16 = unsigned short;
using f16 = _Float16;
typedef __attribute__((ext_vector_type(8))) f16 half8;   // MFMA A/B frag (4 VGPR)
typedef __attribute__((ext_vector_type(4))) f16 half4;   // 8B
typedef __attribute__((ext_vector_type(4))) float f32x4; // MFMA C/D frag
typedef __attribute__((ext_vector_type(4))) unsigned int u32x4;

// XOR involution on 16B slots within a row: spreads K-slots across banks
#define GSWZ(r) ((((r) & 3)) ^ (((r) >> 2) & 3))

typedef const __attribute__((address_space(1))) unsigned int* gas1;
typedef __attribute__((address_space(3))) unsigned int* las3;
__device__ __forceinline__ void gload16(const void* g, void* l){
  __builtin_amdgcn_global_load_lds((gas1)g, (las3)l, 16, 0, 0);
}

// ---------------- fp32 -> fp16 ----------------
__global__ __launch_bounds__(256)
void tofp16_kernel(const float* __restrict__ src, f16* __restrict__ dst, int n4){
  const int stride = gridDim.x * 256;
  for (int i = blockIdx.x*256 + threadIdx.x; i < n4; i += stride){
    float4 v = ((const float4*)src)[i];
    half4 h; h[0]=(f16)v.x; h[1]=(f16)v.y; h[2]=(f16)v.z; h[3]=(f16)v.w;
    ((half4*)dst)[i] = h;
  }
}

// =================================================================
// 128x128 NT GEMM, 256 threads (4 waves 2x2), BK=32, 3-deep LDS
// pipeline (2 tiles lookahead), counted vmcnt, 3 blocks/CU,
// XCD swizzle with A-panel reuse.
// OMODE 0: merged QKV proj. z=proj: B=W[z], out f16 = acc + bias[z]
// OMODE 1: S->P'' = exp(S - M_blk) f16 out; pm/pz partials (f0,f1)
// OMODE 2: PV: z=batch, A-frags scaled by cs[rb][t], out f16 = acc
// =================================================================
template<int OMODE>
__global__ __launch_bounds__(256, 3)
void gemmk(const f16* __restrict__ A, int lda, long sA,
           const f16* __restrict__ B, int ldb, long sB,
           void* __restrict__ Out, int ldc, long sC,
           const float* __restrict__ aux, int Kdim,
           float* __restrict__ f0, float* __restrict__ f1,
           const f16* __restrict__ cs)
{
  __shared__ f16 lA[3][128*32];    // 24 KB
  __shared__ f16 lB[3][128*32];    // 24 KB
  __shared__ float smx[4][4][16], szx[4][4][16];

  // XCD swizzle (nwg % 8 == 0 on all our grids): XCD k owns a contiguous
  // work range decoded by-FASTEST so consecutive works share the A-panel.
  const int nx = gridDim.x, ny = gridDim.y, nwg = nx * ny, cpx = nwg >> 3;
  int h = blockIdx.x + nx * blockIdx.y;
  h = (h & 7) * cpx + (h >> 3);
  const int bx = h / ny, by = h % ny;

  const int b = blockIdx.z;
  const f16* A_ = A + (size_t)b * sA;
  const f16* B_ = B + (size_t)b * sB;
  const int m0 = bx * 128, n0 = by * 128;
  const int tid = threadIdx.x, lane = tid & 63, wave = tid >> 6;
  const int wm = wave >> 1, wn = wave & 1;

  // staging: chunk c -> row=c>>2, dest slot c&3 (LDS linear),
  // SOURCE slot = (c&3) ^ GSWZ(row)  [involution]
  const int c0 = tid, c1 = 256 + tid;
  const int r0 = c0 >> 2, s0 = (c0 & 3) ^ GSWZ(r0);
  const int r1 = c1 >> 2, s1 = (c1 & 3) ^ GSWZ(r1);
  const size_t ga0 = (size_t)(m0 + r0) * lda + s0 * 8;
  const size_t ga1 = (size_t)(m0 + r1) * lda + s1 * 8;
  const size_t gb0 = (size_t)(n0 + r0) * ldb + s0 * 8;
  const size_t gb1 = (size_t)(n0 + r1) * ldb + s1 * 8;

  f32x4 acc[4][4] = {};
  const int NT = Kdim >> 5;

  auto STAGE = [&](int u, int kt){
    gload16(A_ + ga0 + kt, &lA[u][c0*8]);
    gload16(A_ + ga1 + kt, &lA[u][c1*8]);
    gload16(B_ + gb0 + kt, &lB[u][c0*8]);
    gload16(B_ + gb1 + kt, &lB[u][c1*8]);
  };
  STAGE(0, 0); STAGE(1, 32);     // 8 loads/wave in flight (2 tiles ahead)

  const int frow = lane & 15;
  const int rsl = (((lane >> 4) ^ GSWZ(frow)) & 3) * 8;   // swizzled LDS slot
  const int tsl = (lane >> 4) * 8;                        // logical K slot
  const int offA = (wm*64 + frow)*32 + rsl;
  const int offB = (wn*64 + frow)*32 + rsl;
  const f16* cb = (OMODE == 2) ? (cs + ((size_t)b * NQC + bx) * TT + tsl) : nullptr;

  int u = 0;
  for (int t = 0; t < NT; ++t){
    int u2 = u + 2; if (u2 >= 3) u2 -= 3;
    __builtin_amdgcn_s_barrier();            // readers of buf[u2] (iter t-1) done
    __builtin_amdgcn_sched_barrier(0);

    u32x4 ccu;
    if constexpr (OMODE == 2){
      // issue BEFORE stage so vmcnt(8) retires {stage_t(4), cc(1)} together;
      // inline asm keeps the compiler from inserting its own drain wait.
      const f16* ccp = cb + t * 32;
      asm volatile("global_load_dwordx4 %0, %1, off"
                   : "=v"(ccu) : "v"(ccp) : "memory");
    }
    if (t + 2 < NT) STAGE(u2, (t + 2) * 32);
    const int rem = NT - 1 - t;
    if (rem >= 2)      asm volatile("s_waitcnt vmcnt(8)" ::: "memory");
    else if (rem == 1) asm volatile("s_waitcnt vmcnt(4)" ::: "memory");
    else               asm volatile("s_waitcnt vmcnt(0)" ::: "memory");
    __builtin_amdgcn_s_barrier();            // tile-t landed for all waves
    __builtin_amdgcn_sched_barrier(0);

    const f16* tA = &lA[u][0] + offA;
    const f16* tB = &lB[u][0] + offB;
    half8 af[4], bf[4];
#pragma unroll
    for (int i = 0; i < 4; ++i) af[i] = *(const half8*)(tA + i*512);
#pragma unroll
    for (int j = 0; j < 4; ++j) bf[j] = *(const half8*)(tB + j*512);
    if constexpr (OMODE == 2){
      half8 cc; memcpy(&cc, &ccu, 16);       // P = P'' * c, folded into A-frags
#pragma unroll
      for (int i = 0; i < 4; ++i) af[i] *= cc;
    }
    __builtin_amdgcn_s_setprio(1);
#pragma unroll
    for (int i = 0; i < 4; ++i)
#pragma unroll
      for (int j = 0; j < 4; ++j)
        acc[i][j] = __builtin_amdgcn_mfma_f32_16x16x32_f16(af[i], bf[j], acc[i][j], 0,0,0);
    __builtin_amdgcn_s_setprio(0);
    u = (u + 1 == 3) ? 0 : u + 1;
  }

  // epilogue; C/D layout: col = lane&15, row = (lane>>4)*4 + r  [m89 verified]
  const int kq4 = (lane >> 4) * 4;
  if constexpr (OMODE == 0 || OMODE == 2){
    f16* O = (f16*)Out + (size_t)b * sC;
#pragma unroll
    for (int j = 0; j < 4; ++j){
      const int gc = n0 + wn*64 + j*16 + frow;
      float bias_v = 0.f;
      if constexpr (OMODE == 0) bias_v = aux[b*DD + gc];
#pragma unroll
      for (int i = 0; i < 4; ++i)
#pragma unroll
        for (int r = 0; r < 4; ++r){
          const int gr = m0 + wm*64 + i*16 + kq4 + r;
          O[(size_t)gr*ldc + gc] = (f16)(acc[i][j][r] + bias_v);
        }
    }
  } else {
    // S -> P'' = exp(S - M_blk) f16, + per-(rowblock,column) partials
    f16* O = (f16*)Out + (size_t)b * sC;
    float Mb[4], Zb[4];
#pragma unroll
    for (int j = 0; j < 4; ++j){
      float mx = acc[0][j][0];
#pragma unroll
      for (int i = 0; i < 4; ++i)
#pragma unroll
        for (int r = 0; r < 4; ++r) mx = fmaxf(mx, acc[i][j][r]);
      mx = fmaxf(mx, __shfl_xor(mx, 16, 64));
      mx = fmaxf(mx, __shfl_xor(mx, 32, 64));
      if (lane < 16) smx[wave][j][lane] = mx;
      Mb[j] = mx;
    }
    __syncthreads();
#pragma unroll
    for (int j = 0; j < 4; ++j)
      Mb[j] = fmaxf(Mb[j], smx[wave ^ 2][j][frow]);   // block-level column max
#pragma unroll
    for (int j = 0; j < 4; ++j){
      const int gc = n0 + wn*64 + j*16 + frow;
      float zz = 0.f;
#pragma unroll
      for (int i = 0; i < 4; ++i)
#pragma unroll
        for (int r = 0; r < 4; ++r){
          const int gr = m0 + wm*64 + i*16 + kq4 + r;
          float e = __expf(acc[i][j][r] - Mb[j]);
          zz += e;
          O[(size_t)gr*ldc + gc] = (f16)e;
        }
      zz += __shfl_xor(zz, 16, 64);
      zz += __shfl_xor(zz, 32, 64);
      if (lane < 16) szx[wave][j][lane] = zz;
      Zb[j] = zz;
    }
    __syncthreads();
    if (wm == 0 && lane < 16){
#pragma unroll
      for (int j = 0; j < 4; ++j){
        const int gc = n0 + wn*64 + j*16 + lane;
        size_t o = ((size_t)b * NQC + bx) * TT + gc;
        f0[o] = Mb[j];
        f1[o] = Zb[j] + szx[wave + 2][j][lane];
      }
    }
  }
}

// ------- merge NQC partials; emit c[rb][t] = exp(pm - M) * zinv as f16 -------
__global__ __launch_bounds__(256)
void statsB_kernel(const float* __restrict__ pm, const float* __restrict__ pz,
                   f16* __restrict__ c){
  const int b = blockIdx.y;
  const int t = blockIdx.x * 256 + threadIdx.x;
  float am[NQC], az[NQC];
#pragma unroll
  for (int k = 0; k < NQC; ++k){
    size_t o = ((size_t)b * NQC + k) * TT + t;
    am[k] = pm[o]; az[k] = pz[o];
  }
  float M = am[0];
#pragma unroll
  for (int k = 1; k < NQC; ++k) M = fmaxf(M, am[k]);
  float Z = 0.f;
#pragma unroll
  for (int k = 0; k < NQC; ++k) Z += az[k] * __expf(am[k] - M);
  const float zi = 1.f / (Z * 27.712812921102035f);  // 1/(Z*sqrt(768))
#pragma unroll
  for (int k = 0; k < NQC; ++k)
    c[((size_t)b * NQC + k) * TT + t] = (f16)(__expf(am[k] - M) * zi);
}

// ---------------- V [t,v] -> Vt [v,t] (per local batch z) ----------------
__global__ __launch_bounds__(256)
void transp_kernel(const u16* __restrict__ V, u16* __restrict__ Vt){
  const int b = blockIdx.z;
  const int t0 = blockIdx.x * 64, v0 = blockIdx.y * 64;
  const u16* Vb = V + (size_t)b * TT * DD;
  u16* Vtb = Vt + (size_t)b * DD * TT;
  __shared__ u16 tile[64][66];
  const int tid = threadIdx.x;
#pragma unroll
  for (int i = 0; i < 4; ++i){
    int cI = i*256 + tid;
    int r = cI >> 4, c4 = (cI & 15) * 4;
    ushort4 u = *(const ushort4*)&Vb[(size_t)(t0 + r) * DD + v0 + c4];
    tile[r][c4+0] = u.x; tile[r][c4+1] = u.y; tile[r][c4+2] = u.z; tile[r][c4+3] = u.w;
  }
  __syncthreads();
#pragma unroll
  for (int i = 0; i < 4; ++i){
    int cI = i*256 + tid;
    int vr = cI >> 4, t4 = (cI & 15) * 4;
    ushort4 u;
    u.x = tile[t4+0][vr]; u.y = tile[t4+1][vr]; u.z = tile[t4+2][vr]; u.w = tile[t4+3][vr];
    *(ushort4*)&Vtb[(size_t)(v0 + vr) * TT + t0 + t4] = u;
  }
}

// ------- residual + LayerNorm: out = LN(applied_f16 + x) -------
__global__ __launch_bounds__(192)
void ln2_kernel(const half4* __restrict__ applied, const float4* __restrict__ x,
                const float4* __restrict__ gamma4, const float4* __restrict__ beta4,
                float4* __restrict__ out){
  const size_t base = (size_t)blockIdx.x * (DD/4);
  const int cc = threadIdx.x;          // 0..191
  half4 a4 = applied[base + cc];
  float4 x4 = x[base + cc];
  float y0 = (float)a4[0] + x4.x;
  float y1 = (float)a4[1] + x4.y;
  float y2 = (float)a4[2] + x4.z;
  float y3 = (float)a4[3] + x4.w;
  float s = y0+y1+y2+y3;
  float sq = y0*y0+y1*y1+y2*y2+y3*y3;
#pragma unroll
  for (int off = 32; off > 0; off >>= 1){
    s  += __shfl_down(s,  off, 64);
    sq += __shfl_down(sq, off, 64);
  }
  __shared__ float rs_[3], rq_[3];
  const int lane = threadIdx.x & 63, w = threadIdx.x >> 6;
  if (lane == 0){ rs_[w] = s; rq_[w] = sq; }
  __syncthreads();
  const float S_ = rs_[0]+rs_[1]+rs_[2];
  const float Q_ = rq_[0]+rq_[1]+rq_[2];
  const float mu  = S_ * (1.f/DD);
  const float var = Q_ * (1.f/DD) - mu*mu;
  const float rstd = rsqrtf(var + 1e-5f);
  float4 g = gamma4[cc], be = beta4[cc], o;
  o.x = (y0 - mu)*rstd*g.x + be.x;
  o.y = (y1 - mu)*rstd*g.y + be.y;
  o.z = (y2 - mu)*rstd*g.z + be.z;
  o.w = (y3 - mu)*rstd*g.w + be.w;
  out[base + cc] = o;
}

extern "C" void kernel_launch(void* const* d_in, const int* in_sizes, int n_in,
                              void* d_out, int out_size, void* d_ws, size_t ws_size,
                              hipStream_t stream)
{
  const float* x    = (const float*)d_in[0];
  const float* Wk   = (const float*)d_in[1];
  const float* bk   = (const float*)d_in[2];
  const float* Wq   = (const float*)d_in[3];
  const float* bq   = (const float*)d_in[4];
  const float* Wv   = (const float*)d_in[5];
  const float* bv   = (const float*)d_in[6];
  const float* gamma= (const float*)d_in[7];
  const float* beta = (const float*)d_in[8];
  float* out = (float*)d_out;

  const size_t PW = (size_t)DD*DD*2;    // f16 weight plane
  const size_t PB = (size_t)TT*DD*2;    // f16 activation plane per batch
  const size_t T4 = (size_t)TT*4;
  auto al = [](size_t n){ return (n + 255) & ~(size_t)255; };

  auto need = [&](int G)->size_t{
    size_t t = al(3*PW) + al(3*DD*4) + al((size_t)BB*PB) + al((size_t)BB*TT*TT*2)
             + al((size_t)G*PB) + al(3*(size_t)G*PB)
             + 2*al((size_t)G*NQC*T4) + al((size_t)BB*NQC*TT*2);
    if (4*(size_t)G*PB < (size_t)BB*PB) t += al((size_t)BB*PB);  // applied alias shortfall
    return t;
  };

  int G = 0;
  for (int g : {8, 4, 2, 1}) if (need(g) <= ws_size){ G = g; break; }
  if (G == 0) return;

  char* p = (char*)d_ws;
  auto alloc = [&](size_t n)->char*{ char* r = p; p += (n + 255) & ~(size_t)255; return r; };
  f16*   Wf    = (f16*)alloc(3*PW);            // [Wq;Wk;Wv]
  float* biasf = (float*)alloc(3*DD*4);        // [bq;bk;bv]
  f16*   Vt    = (f16*)alloc((size_t)BB*PB);
  f16*   P16   = (f16*)alloc((size_t)BB*TT*TT*2);
  f16*   Xc    = (f16*)alloc((size_t)G*PB);
  f16*   QKVc  = (f16*)alloc(3*(size_t)G*PB);
  float* pm    = (float*)alloc((size_t)G*NQC*T4);
  float* pz    = (float*)alloc((size_t)G*NQC*T4);
  f16*   cbuf  = (f16*)alloc((size_t)BB*NQC*TT*2);
  f16* applied = (4*(size_t)G*PB >= (size_t)BB*PB) ? Xc
               : (f16*)alloc((size_t)BB*PB);    // aliases dead Xc+QKVc when G>=4
  f16* Qc = QKVc, *Kc = QKVc + (size_t)G*TT*DD, *Vc = QKVc + 2*(size_t)G*TT*DD;

  tofp16_kernel<<<288, 256, 0, stream>>>(Wq, Wf,             DD*DD/4);
  tofp16_kernel<<<288, 256, 0, stream>>>(Wk, Wf +   DD*DD,   DD*DD/4);
  tofp16_kernel<<<288, 256, 0, stream>>>(Wv, Wf + 2*DD*DD,   DD*DD/4);
  hipMemcpyAsync(biasf,        bq, DD*4, hipMemcpyDeviceToDevice, stream);
  hipMemcpyAsync(biasf +   DD, bk, DD*4, hipMemcpyDeviceToDevice, stream);
  hipMemcpyAsync(biasf + 2*DD, bv, DD*4, hipMemcpyDeviceToDevice, stream);

  const int nRows = G * TT;
  for (int b0 = 0; b0 < BB; b0 += G){
    tofp16_kernel<<<2048, 256, 0, stream>>>(x + (size_t)b0*TT*DD, Xc, nRows*DD/4);

    dim3 gp(nRows/128, DD/128, 3);
    gemmk<0><<<gp, 256, 0, stream>>>(Xc, DD, 0, Wf, DD, (long)DD*DD,
                                     QKVc, DD, (long)G*TT*DD, biasf, DD,
                                     nullptr, nullptr, nullptr);

    transp_kernel<<<dim3(TT/64, DD/64, G), 256, 0, stream>>>(
        (const u16*)Vc, (u16*)(Vt + (size_t)b0*DD*TT));

    // S = Q K^T -> P'' f16 directly into P16, + stats partials
    dim3 gs(TT/128, TT/128, G);
    gemmk<1><<<gs, 256, 0, stream>>>(Qc, DD, (long)TT*DD, Kc, DD, (long)TT*DD,
                                     P16 + (size_t)b0*TT*TT, TT, (long)TT*TT,
                                     nullptr, DD, pm, pz, nullptr);

    statsB_kernel<<<dim3(TT/256, G), 256, 0, stream>>>(
        pm, pz, cbuf + (size_t)b0*NQC*TT);
  }

  // PV over all batches -> applied f16 (softmax correction folded into A-frags)
  dim3 gpv(TT/128, DD/128, BB);
  gemmk<2><<<gpv, 256, 0, stream>>>(P16, TT, (long)TT*TT, Vt, TT, (long)DD*TT,
                                    applied, DD, (long)TT*DD, nullptr, TT,
                                    nullptr, nullptr, cbuf);

  ln2_kernel<<<BT, 192, 0, stream>>>((const half4*)applied, (const float4*)x,
                                     (const float4*)gamma, (const float4*)beta,
                                     (float4*)out);
}

// Round 10
// 568.824 us; speedup vs baseline: 1.6396x; 1.0208x over previous
//
#include <hip/hip_runtime.h>
#include <hip/hip_fp16.h>

// Problem constants (reference: B=16, T=2048, D=768)
#define DD 768
#define BB 16
#define TT 2048
#define BT (BB*TT)   // 32768
#define NQC 16       // 128-row blocks per batch for column-softmax stats

using u16 = unsigned short;
using f16 = _Float16;
typedef __attribute__((ext_vector_type(8))) f16 half8;   // MFMA A/B frag (4 VGPR)
typedef __attribute__((ext_vector_type(4))) f16 half4;   // 8B
typedef __attribute__((ext_vector_type(4))) float f32x4; // MFMA C/D frag

// XOR involution on 16B slots within a row: spreads K-slots across banks
#define GSWZ(r) ((((r) & 3)) ^ (((r) >> 2) & 3))

typedef const __attribute__((address_space(1))) unsigned int* gas1;
typedef __attribute__((address_space(3))) unsigned int* las3;
__device__ __forceinline__ void gload16(const void* g, void* l){
  __builtin_amdgcn_global_load_lds((gas1)g, (las3)l, 16, 0, 0);
}

// ---------------- fp32 -> fp16 ----------------
__global__ __launch_bounds__(256)
void tofp16_kernel(const float* __restrict__ src, f16* __restrict__ dst, int n4){
  const int stride = gridDim.x * 256;
  for (int i = blockIdx.x*256 + threadIdx.x; i < n4; i += stride){
    float4 v = ((const float4*)src)[i];
    half4 h; h[0]=(f16)v.x; h[1]=(f16)v.y; h[2]=(f16)v.z; h[3]=(f16)v.w;
    ((half4*)dst)[i] = h;
  }
}

// =================================================================
// 128x128 NT GEMM, 256 threads (4 waves 2x2), BK=32, 3-deep LDS
// pipeline (2 tiles lookahead), counted vmcnt, 3 blocks/CU,
// XCD swizzle with A-panel reuse.
// OMODE 0: merged QKV proj. z=proj: B=W[z], out f16 = acc + bias[z]
// OMODE 1: S->P'' = exp(S - M_blk) f16 out; pm/pz partials (f0,f1)
// OMODE 2: PV: z=batch, A-frags scaled by cs[rb][t] (LDS-preloaded),
//          out f16 = acc
// =================================================================
template<int OMODE>
__global__ __launch_bounds__(256, 3)
void gemmk(const f16* __restrict__ A, int lda, long sA,
           const f16* __restrict__ B, int ldb, long sB,
           void* __restrict__ Out, int ldc, long sC,
           const float* __restrict__ aux, int Kdim,
           float* __restrict__ f0, float* __restrict__ f1,
           const f16* __restrict__ cs)
{
  __shared__ f16 lA[3][128*32];    // 24 KB
  __shared__ f16 lB[3][128*32];    // 24 KB
  // conditionally sized so every OMODE stays under 53.3 KB (3 blocks/CU)
  __shared__ float smx[OMODE==1 ? 4 : 1][4][16], szx[OMODE==1 ? 4 : 1][4][16];
  __shared__ f16 lCC[OMODE==2 ? 2048 : 8];     // c-row for this q-rowblock

  // XCD swizzle (nwg % 8 == 0 on all our grids): XCD k owns a contiguous
  // work range decoded by-FASTEST so consecutive works share the A-panel.
  const int nx = gridDim.x, ny = gridDim.y, nwg = nx * ny, cpx = nwg >> 3;
  int h = blockIdx.x + nx * blockIdx.y;
  h = (h & 7) * cpx + (h >> 3);
  const int bx = h / ny, by = h % ny;

  const int b = blockIdx.z;
  const f16* A_ = A + (size_t)b * sA;
  const f16* B_ = B + (size_t)b * sB;
  const int m0 = bx * 128, n0 = by * 128;
  const int tid = threadIdx.x, lane = tid & 63, wave = tid >> 6;
  const int wm = wave >> 1, wn = wave & 1;

  // staging: chunk c -> row=c>>2, dest slot c&3 (LDS linear),
  // SOURCE slot = (c&3) ^ GSWZ(row)  [involution]
  const int c0 = tid, c1 = 256 + tid;
  const int r0 = c0 >> 2, s0 = (c0 & 3) ^ GSWZ(r0);
  const int r1 = c1 >> 2, s1 = (c1 & 3) ^ GSWZ(r1);
  const size_t ga0 = (size_t)(m0 + r0) * lda + s0 * 8;
  const size_t ga1 = (size_t)(m0 + r1) * lda + s1 * 8;
  const size_t gb0 = (size_t)(n0 + r0) * ldb + s0 * 8;
  const size_t gb1 = (size_t)(n0 + r1) * ldb + s1 * 8;

  f32x4 acc[4][4] = {};
  const int NT = Kdim >> 5;

  auto STAGE = [&](int u, int kt){
    gload16(A_ + ga0 + kt, &lA[u][c0*8]);
    gload16(A_ + ga1 + kt, &lA[u][c1*8]);
    gload16(B_ + gb0 + kt, &lB[u][c0*8]);
    gload16(B_ + gb1 + kt, &lB[u][c1*8]);
  };

  if constexpr (OMODE == 2){
    // preload this block's softmax-correction row c[rb=bx][0..2047] (4 KB)
    const f16* cb = cs + ((size_t)b * NQC + bx) * TT;
    ((half8*)lCC)[tid] = ((const half8*)cb)[tid];
    __syncthreads();   // lgkm drain: lCC visible to all waves before the loop
  }

  STAGE(0, 0); STAGE(1, 32);     // 8 loads/wave in flight (2 tiles ahead)

  const int frow = lane & 15;
  const int rsl = (((lane >> 4) ^ GSWZ(frow)) & 3) * 8;   // swizzled LDS slot
  const int tsl = (lane >> 4) * 8;                        // logical K slot
  const int offA = (wm*64 + frow)*32 + rsl;
  const int offB = (wn*64 + frow)*32 + rsl;

  int u = 0;
  for (int t = 0; t < NT; ++t){
    int u2 = u + 2; if (u2 >= 3) u2 -= 3;
    __builtin_amdgcn_s_barrier();            // readers of buf[u2] (iter t-1) done
    __builtin_amdgcn_sched_barrier(0);
    if (t + 2 < NT) STAGE(u2, (t + 2) * 32);
    const int rem = NT - 1 - t;
    if (rem >= 2)      asm volatile("s_waitcnt vmcnt(8)" ::: "memory");
    else if (rem == 1) asm volatile("s_waitcnt vmcnt(4)" ::: "memory");
    else               asm volatile("s_waitcnt vmcnt(0)" ::: "memory");
    __builtin_amdgcn_s_barrier();            // tile-t landed for all waves
    __builtin_amdgcn_sched_barrier(0);

    const f16* tA = &lA[u][0] + offA;
    const f16* tB = &lB[u][0] + offB;
    half8 af[4], bf[4];
#pragma unroll
    for (int i = 0; i < 4; ++i) af[i] = *(const half8*)(tA + i*512);
#pragma unroll
    for (int j = 0; j < 4; ++j) bf[j] = *(const half8*)(tB + j*512);
    if constexpr (OMODE == 2){
      half8 cc = *(const half8*)&lCC[t*32 + tsl];   // P = P'' * c, folded into A
#pragma unroll
      for (int i = 0; i < 4; ++i) af[i] *= cc;
    }
    __builtin_amdgcn_s_setprio(1);
#pragma unroll
    for (int i = 0; i < 4; ++i)
#pragma unroll
      for (int j = 0; j < 4; ++j)
        acc[i][j] = __builtin_amdgcn_mfma_f32_16x16x32_f16(af[i], bf[j], acc[i][j], 0,0,0);
    __builtin_amdgcn_s_setprio(0);
    u = (u + 1 == 3) ? 0 : u + 1;
  }

  // epilogue; C/D layout: col = lane&15, row = (lane>>4)*4 + r  [m89 verified]
  const int kq4 = (lane >> 4) * 4;
  if constexpr (OMODE == 0 || OMODE == 2){
    f16* O = (f16*)Out + (size_t)b * sC;
#pragma unroll
    for (int j = 0; j < 4; ++j){
      const int gc = n0 + wn*64 + j*16 + frow;
      float bias_v = 0.f;
      if constexpr (OMODE == 0) bias_v = aux[b*DD + gc];
#pragma unroll
      for (int i = 0; i < 4; ++i)
#pragma unroll
        for (int r = 0; r < 4; ++r){
          const int gr = m0 + wm*64 + i*16 + kq4 + r;
          O[(size_t)gr*ldc + gc] = (f16)(acc[i][j][r] + bias_v);
        }
    }
  } else {
    // S -> P'' = exp(S - M_blk) f16, + per-(rowblock,column) partials
    f16* O = (f16*)Out + (size_t)b * sC;
    float Mb[4], Zb[4];
#pragma unroll
    for (int j = 0; j < 4; ++j){
      float mx = acc[0][j][0];
#pragma unroll
      for (int i = 0; i < 4; ++i)
#pragma unroll
        for (int r = 0; r < 4; ++r) mx = fmaxf(mx, acc[i][j][r]);
      mx = fmaxf(mx, __shfl_xor(mx, 16, 64));
      mx = fmaxf(mx, __shfl_xor(mx, 32, 64));
      if (lane < 16) smx[wave][j][lane] = mx;
      Mb[j] = mx;
    }
    __syncthreads();
#pragma unroll
    for (int j = 0; j < 4; ++j)
      Mb[j] = fmaxf(Mb[j], smx[wave ^ 2][j][frow]);   // block-level column max
#pragma unroll
    for (int j = 0; j < 4; ++j){
      const int gc = n0 + wn*64 + j*16 + frow;
      float zz = 0.f;
#pragma unroll
      for (int i = 0; i < 4; ++i)
#pragma unroll
        for (int r = 0; r < 4; ++r){
          const int gr = m0 + wm*64 + i*16 + kq4 + r;
          float e = __expf(acc[i][j][r] - Mb[j]);
          zz += e;
          O[(size_t)gr*ldc + gc] = (f16)e;
        }
      zz += __shfl_xor(zz, 16, 64);
      zz += __shfl_xor(zz, 32, 64);
      if (lane < 16) szx[wave][j][lane] = zz;
      Zb[j] = zz;
    }
    __syncthreads();
    if (wm == 0 && lane < 16){
#pragma unroll
      for (int j = 0; j < 4; ++j){
        const int gc = n0 + wn*64 + j*16 + lane;
        size_t o = ((size_t)b * NQC + bx) * TT + gc;
        f0[o] = Mb[j];
        f1[o] = Zb[j] + szx[wave + 2][j][lane];
      }
    }
  }
}

// ------- merge NQC partials; emit c[rb][t] = exp(pm - M) * zinv as f16 -------
__global__ __launch_bounds__(256)
void statsB_kernel(const float* __restrict__ pm, const float* __restrict__ pz,
                   f16* __restrict__ c){
  const int b = blockIdx.y;
  const int t = blockIdx.x * 256 + threadIdx.x;
  float am[NQC], az[NQC];
#pragma unroll
  for (int k = 0; k < NQC; ++k){
    size_t o = ((size_t)b * NQC + k) * TT + t;
    am[k] = pm[o]; az[k] = pz[o];
  }
  float M = am[0];
#pragma unroll
  for (int k = 1; k < NQC; ++k) M = fmaxf(M, am[k]);
  float Z = 0.f;
#pragma unroll
  for (int k = 0; k < NQC; ++k) Z += az[k] * __expf(am[k] - M);
  const float zi = 1.f / (Z * 27.712812921102035f);  // 1/(Z*sqrt(768))
#pragma unroll
  for (int k = 0; k < NQC; ++k)
    c[((size_t)b * NQC + k) * TT + t] = (f16)(__expf(am[k] - M) * zi);
}

// ---------------- V [t,v] -> Vt [v,t] (per local batch z) ----------------
__global__ __launch_bounds__(256)
void transp_kernel(const u16* __restrict__ V, u16* __restrict__ Vt){
  const int b = blockIdx.z;
  const int t0 = blockIdx.x * 64, v0 = blockIdx.y * 64;
  const u16* Vb = V + (size_t)b * TT * DD;
  u16* Vtb = Vt + (size_t)b * DD * TT;
  __shared__ u16 tile[64][66];
  const int tid = threadIdx.x;
#pragma unroll
  for (int i = 0; i < 4; ++i){
    int cI = i*256 + tid;
    int r = cI >> 4, c4 = (cI & 15) * 4;
    ushort4 u = *(const ushort4*)&Vb[(size_t)(t0 + r) * DD + v0 + c4];
    tile[r][c4+0] = u.x; tile[r][c4+1] = u.y; tile[r][c4+2] = u.z; tile[r][c4+3] = u.w;
  }
  __syncthreads();
#pragma unroll
  for (int i = 0; i < 4; ++i){
    int cI = i*256 + tid;
    int vr = cI >> 4, t4 = (cI & 15) * 4;
    ushort4 u;
    u.x = tile[t4+0][vr]; u.y = tile[t4+1][vr]; u.z = tile[t4+2][vr]; u.w = tile[t4+3][vr];
    *(ushort4*)&Vtb[(size_t)(v0 + vr) * TT + t0 + t4] = u;
  }
}

// ------- residual + LayerNorm: out = LN(applied_f16 + x) -------
__global__ __launch_bounds__(192)
void ln2_kernel(const half4* __restrict__ applied, const float4* __restrict__ x,
                const float4* __restrict__ gamma4, const float4* __restrict__ beta4,
                float4* __restrict__ out){
  const size_t base = (size_t)blockIdx.x * (DD/4);
  const int cc = threadIdx.x;          // 0..191
  half4 a4 = applied[base + cc];
  float4 x4 = x[base + cc];
  float y0 = (float)a4[0] + x4.x;
  float y1 = (float)a4[1] + x4.y;
  float y2 = (float)a4[2] + x4.z;
  float y3 = (float)a4[3] + x4.w;
  float s = y0+y1+y2+y3;
  float sq = y0*y0+y1*y1+y2*y2+y3*y3;
#pragma unroll
  for (int off = 32; off > 0; off >>= 1){
    s  += __shfl_down(s,  off, 64);
    sq += __shfl_down(sq, off, 64);
  }
  __shared__ float rs_[3], rq_[3];
  const int lane = threadIdx.x & 63, w = threadIdx.x >> 6;
  if (lane == 0){ rs_[w] = s; rq_[w] = sq; }
  __syncthreads();
  const float S_ = rs_[0]+rs_[1]+rs_[2];
  const float Q_ = rq_[0]+rq_[1]+rq_[2];
  const float mu  = S_ * (1.f/DD);
  const float var = Q_ * (1.f/DD) - mu*mu;
  const float rstd = rsqrtf(var + 1e-5f);
  float4 g = gamma4[cc], be = beta4[cc], o;
  o.x = (y0 - mu)*rstd*g.x + be.x;
  o.y = (y1 - mu)*rstd*g.y + be.y;
  o.z = (y2 - mu)*rstd*g.z + be.z;
  o.w = (y3 - mu)*rstd*g.w + be.w;
  out[base + cc] = o;
}

extern "C" void kernel_launch(void* const* d_in, const int* in_sizes, int n_in,
                              void* d_out, int out_size, void* d_ws, size_t ws_size,
                              hipStream_t stream)
{
  const float* x    = (const float*)d_in[0];
  const float* Wk   = (const float*)d_in[1];
  const float* bk   = (const float*)d_in[2];
  const float* Wq   = (const float*)d_in[3];
  const float* bq   = (const float*)d_in[4];
  const float* Wv   = (const float*)d_in[5];
  const float* bv   = (const float*)d_in[6];
  const float* gamma= (const float*)d_in[7];
  const float* beta = (const float*)d_in[8];
  float* out = (float*)d_out;

  const size_t PW = (size_t)DD*DD*2;    // f16 weight plane
  const size_t PB = (size_t)TT*DD*2;    // f16 activation plane per batch
  const size_t T4 = (size_t)TT*4;
  auto al = [](size_t n){ return (n + 255) & ~(size_t)255; };

  auto need = [&](int G)->size_t{
    size_t t = al(3*PW) + al(3*DD*4) + al((size_t)BB*PB) + al((size_t)BB*TT*TT*2)
             + al((size_t)G*PB) + al(3*(size_t)G*PB)
             + 2*al((size_t)G*NQC*T4) + al((size_t)BB*NQC*TT*2);
    if (4*(size_t)G*PB < (size_t)BB*PB) t += al((size_t)BB*PB);  // applied alias shortfall
    return t;
  };

  int G = 0;
  for (int g : {16, 8, 4, 2, 1}) if (need(g) <= ws_size){ G = g; break; }
  if (G == 0) return;

  char* p = (char*)d_ws;
  auto alloc = [&](size_t n)->char*{ char* r = p; p += (n + 255) & ~(size_t)255; return r; };
  f16*   Wf    = (f16*)alloc(3*PW);            // [Wq;Wk;Wv]
  float* biasf = (float*)alloc(3*DD*4);        // [bq;bk;bv]
  f16*   Vt    = (f16*)alloc((size_t)BB*PB);
  f16*   P16   = (f16*)alloc((size_t)BB*TT*TT*2);
  f16*   Xc    = (f16*)alloc((size_t)G*PB);
  f16*   QKVc  = (f16*)alloc(3*(size_t)G*PB);
  float* pm    = (float*)alloc((size_t)G*NQC*T4);
  float* pz    = (float*)alloc((size_t)G*NQC*T4);
  f16*   cbuf  = (f16*)alloc((size_t)BB*NQC*TT*2);
  // applied (BB*PB) lives over Xc+QKVc (contiguous, dead at PV time) when it fits
  f16* applied = (4*(size_t)G*PB >= (size_t)BB*PB) ? Xc
               : (f16*)alloc((size_t)BB*PB);
  f16* Qc = QKVc, *Kc = QKVc + (size_t)G*TT*DD, *Vc = QKVc + 2*(size_t)G*TT*DD;

  tofp16_kernel<<<288, 256, 0, stream>>>(Wq, Wf,             DD*DD/4);
  tofp16_kernel<<<288, 256, 0, stream>>>(Wk, Wf +   DD*DD,   DD*DD/4);
  tofp16_kernel<<<288, 256, 0, stream>>>(Wv, Wf + 2*DD*DD,   DD*DD/4);
  hipMemcpyAsync(biasf,        bq, DD*4, hipMemcpyDeviceToDevice, stream);
  hipMemcpyAsync(biasf +   DD, bk, DD*4, hipMemcpyDeviceToDevice, stream);
  hipMemcpyAsync(biasf + 2*DD, bv, DD*4, hipMemcpyDeviceToDevice, stream);

  const int nRows = G * TT;
  for (int b0 = 0; b0 < BB; b0 += G){
    tofp16_kernel<<<2048, 256, 0, stream>>>(x + (size_t)b0*TT*DD, Xc, nRows*DD/4);

    dim3 gp(nRows/128, DD/128, 3);
    gemmk<0><<<gp, 256, 0, stream>>>(Xc, DD, 0, Wf, DD, (long)DD*DD,
                                     QKVc, DD, (long)G*TT*DD, biasf, DD,
                                     nullptr, nullptr, nullptr);

    transp_kernel<<<dim3(TT/64, DD/64, G), 256, 0, stream>>>(
        (const u16*)Vc, (u16*)(Vt + (size_t)b0*DD*TT));

    // S = Q K^T -> P'' f16 directly into P16, + stats partials
    dim3 gs(TT/128, TT/128, G);
    gemmk<1><<<gs, 256, 0, stream>>>(Qc, DD, (long)TT*DD, Kc, DD, (long)TT*DD,
                                     P16 + (size_t)b0*TT*TT, TT, (long)TT*TT,
                                     nullptr, DD, pm, pz, nullptr);

    statsB_kernel<<<dim3(TT/256, G), 256, 0, stream>>>(
        pm, pz, cbuf + (size_t)b0*NQC*TT);
  }

  // PV over all batches -> applied f16 (softmax correction folded into A-frags)
  dim3 gpv(TT/128, DD/128, BB);
  gemmk<2><<<gpv, 256, 0, stream>>>(P16, TT, (long)TT*TT, Vt, TT, (long)DD*TT,
                                    applied, DD, (long)TT*DD, nullptr, TT,
                                    nullptr, nullptr, cbuf);

  ln2_kernel<<<BT, 192, 0, stream>>>((const half4*)applied, (const float4*)x,
                                     (const float4*)gamma, (const float4*)beta,
                                     (float4*)out);
}

// Round 11
// 562.791 us; speedup vs baseline: 1.6572x; 1.0107x over previous
//
#include <hip/hip_runtime.h>
#include <hip/hip_fp16.h>

// Problem constants (reference: B=16, T=2048, D=768)
#define DD 768
#define BB 16
#define TT 2048
#define BT (BB*TT)   // 32768
#define NQS 8        // 256-row blocks per batch for column-softmax stats

using u16 = unsigned short;
using f16 = _Float16;
typedef __attribute__((ext_vector_type(8))) f16 half8;   // MFMA A/B frag (4 VGPR)
typedef __attribute__((ext_vector_type(4))) f16 half4;   // 8B
typedef __attribute__((ext_vector_type(4))) float f32x4; // MFMA C/D frag

// XOR involution on 16B slots within a row: spreads K-slots across banks
#define GSWZ(r) ((((r) & 3)) ^ (((r) >> 2) & 3))

typedef const __attribute__((address_space(1))) unsigned int* gas1;
typedef __attribute__((address_space(3))) unsigned int* las3;
__device__ __forceinline__ void gload16(const void* g, void* l){
  __builtin_amdgcn_global_load_lds((gas1)g, (las3)l, 16, 0, 0);
}

// ---------------- fp32 -> fp16 ----------------
__global__ __launch_bounds__(256)
void tofp16_kernel(const float* __restrict__ src, f16* __restrict__ dst, int n4){
  const int stride = gridDim.x * 256;
  for (int i = blockIdx.x*256 + threadIdx.x; i < n4; i += stride){
    float4 v = ((const float4*)src)[i];
    half4 h; h[0]=(f16)v.x; h[1]=(f16)v.y; h[2]=(f16)v.z; h[3]=(f16)v.w;
    ((half4*)dst)[i] = h;
  }
}

// =================================================================
// NT GEMM engine, 256 threads (4 waves 2Mx2N), BK=32, 3-deep LDS
// pipeline, counted vmcnt, XCD swizzle with A-panel reuse.
// Geometry per OMODE:
//   OMODE 0 (QKV proj)  : 256x128 block, 8x4 acc/wave, 2 blocks/CU
//   OMODE 1 (S -> P'')  : 256x128 block, 8x4 acc/wave, 2 blocks/CU
//   OMODE 2 (PV)        : 128x128 block, 4x4 acc/wave, 3 blocks/CU
// =================================================================
template<int OMODE>
__global__ __launch_bounds__(256, OMODE==2 ? 3 : 2)
void gemmk(const f16* __restrict__ A, int lda, long sA,
           const f16* __restrict__ B, int ldb, long sB,
           void* __restrict__ Out, int ldc, long sC,
           const float* __restrict__ aux, int Kdim,
           float* __restrict__ f0, float* __restrict__ f1,
           const f16* __restrict__ cs)
{
  constexpr int MR = (OMODE==2) ? 4 : 8;   // m-frag reps per wave
  constexpr int BM = MR * 32;              // block rows (128 or 256)
  constexpr int AC = BM / 64;              // A staging chunks per thread (2 or 4)

  __shared__ f16 lA[3][BM*32];             // 24 or 48 KB
  __shared__ f16 lB[3][128*32];            // 24 KB
  __shared__ float smx[OMODE==1 ? 4 : 1][4][16], szx[OMODE==1 ? 4 : 1][4][16];
  __shared__ f16 lCC[OMODE==2 ? 2048 : 8]; // softmax-correction row (PV)

  // XCD swizzle (nwg % 8 == 0 on all our grids): XCD k owns a contiguous
  // work range decoded by-FASTEST so consecutive works share the A-panel.
  const int nx = gridDim.x, ny = gridDim.y, nwg = nx * ny, cpx = nwg >> 3;
  int h = blockIdx.x + nx * blockIdx.y;
  h = (h & 7) * cpx + (h >> 3);
  const int bx = h / ny, by = h % ny;

  const int b = blockIdx.z;
  const f16* A_ = A + (size_t)b * sA;
  const f16* B_ = B + (size_t)b * sB;
  const int m0 = bx * BM, n0 = by * 128;
  const int tid = threadIdx.x, lane = tid & 63, wave = tid >> 6;
  const int wm = wave >> 1, wn = wave & 1;

  // staging: chunk c -> row=c>>2, dest slot c&3 (LDS linear),
  // SOURCE slot = (c&3) ^ GSWZ(row)  [involution]
  size_t gaO[AC], gbO[2];
#pragma unroll
  for (int k = 0; k < AC; ++k){
    int c = k*256 + tid, r = c >> 2, s = (c & 3) ^ GSWZ(r);
    gaO[k] = (size_t)(m0 + r) * lda + s * 8;
  }
#pragma unroll
  for (int k = 0; k < 2; ++k){
    int c = k*256 + tid, r = c >> 2, s = (c & 3) ^ GSWZ(r);
    gbO[k] = (size_t)(n0 + r) * ldb + s * 8;
  }

  f32x4 acc[MR][4] = {};
  const int NT = Kdim >> 5;

  auto STAGE = [&](int u, int kt){
#pragma unroll
    for (int k = 0; k < AC; ++k) gload16(A_ + gaO[k] + kt, &lA[u][(k*256+tid)*8]);
#pragma unroll
    for (int k = 0; k < 2; ++k)  gload16(B_ + gbO[k] + kt, &lB[u][(k*256+tid)*8]);
  };

  if constexpr (OMODE == 2){
    // preload this block's softmax-correction row: stats rb = bx>>1 (256-row blocks)
    const f16* cb = cs + ((size_t)b * NQS + (bx >> 1)) * TT;
    ((half8*)lCC)[tid] = ((const half8*)cb)[tid];
    __syncthreads();   // lgkm drain: lCC visible to all waves before the loop
  }

  STAGE(0, 0); STAGE(1, 32);   // 2 tiles ahead in flight

  const int frow = lane & 15;
  const int rsl = (((lane >> 4) ^ GSWZ(frow)) & 3) * 8;   // swizzled LDS slot
  const int tsl = (lane >> 4) * 8;                        // logical K slot
  const int offA = (wm*(MR*16) + frow)*32 + rsl;
  const int offB = (wn*64 + frow)*32 + rsl;

  int u = 0;
  for (int t = 0; t < NT; ++t){
    int u2 = u + 2; if (u2 >= 3) u2 -= 3;
    __builtin_amdgcn_s_barrier();            // readers of buf[u2] (iter t-1) done
    __builtin_amdgcn_sched_barrier(0);
    if (t + 2 < NT) STAGE(u2, (t + 2) * 32);
    const int rem = NT - 1 - t;
    if constexpr (AC == 4){   // 6 loads/tile
      if (rem >= 2)      asm volatile("s_waitcnt vmcnt(12)" ::: "memory");
      else if (rem == 1) asm volatile("s_waitcnt vmcnt(6)"  ::: "memory");
      else               asm volatile("s_waitcnt vmcnt(0)"  ::: "memory");
    } else {                  // 4 loads/tile
      if (rem >= 2)      asm volatile("s_waitcnt vmcnt(8)" ::: "memory");
      else if (rem == 1) asm volatile("s_waitcnt vmcnt(4)" ::: "memory");
      else               asm volatile("s_waitcnt vmcnt(0)" ::: "memory");
    }
    __builtin_amdgcn_s_barrier();            // tile-t landed for all waves
    __builtin_amdgcn_sched_barrier(0);

    const f16* tA = &lA[u][0] + offA;
    const f16* tB = &lB[u][0] + offB;
    half8 af[MR], bf[4];
#pragma unroll
    for (int i = 0; i < MR; ++i) af[i] = *(const half8*)(tA + i*512);
#pragma unroll
    for (int j = 0; j < 4; ++j)  bf[j] = *(const half8*)(tB + j*512);
    if constexpr (OMODE == 2){
      half8 cc = *(const half8*)&lCC[t*32 + tsl];   // P = P'' * c, folded into A
#pragma unroll
      for (int i = 0; i < MR; ++i) af[i] *= cc;
    }
    __builtin_amdgcn_s_setprio(1);
#pragma unroll
    for (int i = 0; i < MR; ++i)
#pragma unroll
      for (int j = 0; j < 4; ++j)
        acc[i][j] = __builtin_amdgcn_mfma_f32_16x16x32_f16(af[i], bf[j], acc[i][j], 0,0,0);
    __builtin_amdgcn_s_setprio(0);
    u = (u + 1 == 3) ? 0 : u + 1;
  }

  // epilogue; C/D layout: col = lane&15, row = (lane>>4)*4 + r  [m89 verified]
  const int kq4 = (lane >> 4) * 4;
  if constexpr (OMODE == 0 || OMODE == 2){
    f16* O = (f16*)Out + (size_t)b * sC;
#pragma unroll
    for (int j = 0; j < 4; ++j){
      const int gc = n0 + wn*64 + j*16 + frow;
      float bias_v = 0.f;
      if constexpr (OMODE == 0) bias_v = aux[b*DD + gc];
#pragma unroll
      for (int i = 0; i < MR; ++i)
#pragma unroll
        for (int r = 0; r < 4; ++r){
          const int gr = m0 + wm*(MR*16) + i*16 + kq4 + r;
          O[(size_t)gr*ldc + gc] = (f16)(acc[i][j][r] + bias_v);
        }
    }
  } else {
    // S -> P'' = exp(S - M_blk) f16, + per-(256-rowblock,column) partials
    f16* O = (f16*)Out + (size_t)b * sC;
    float Mb[4], Zb[4];
#pragma unroll
    for (int j = 0; j < 4; ++j){
      float mx = acc[0][j][0];
#pragma unroll
      for (int i = 0; i < MR; ++i)
#pragma unroll
        for (int r = 0; r < 4; ++r) mx = fmaxf(mx, acc[i][j][r]);
      mx = fmaxf(mx, __shfl_xor(mx, 16, 64));
      mx = fmaxf(mx, __shfl_xor(mx, 32, 64));
      if (lane < 16) smx[wave][j][lane] = mx;
      Mb[j] = mx;
    }
    __syncthreads();
#pragma unroll
    for (int j = 0; j < 4; ++j)
      Mb[j] = fmaxf(Mb[j], smx[wave ^ 2][j][frow]);   // block-level column max
#pragma unroll
    for (int j = 0; j < 4; ++j){
      const int gc = n0 + wn*64 + j*16 + frow;
      float zz = 0.f;
#pragma unroll
      for (int i = 0; i < MR; ++i)
#pragma unroll
        for (int r = 0; r < 4; ++r){
          const int gr = m0 + wm*(MR*16) + i*16 + kq4 + r;
          float e = __expf(acc[i][j][r] - Mb[j]);
          zz += e;
          O[(size_t)gr*ldc + gc] = (f16)e;
        }
      zz += __shfl_xor(zz, 16, 64);
      zz += __shfl_xor(zz, 32, 64);
      if (lane < 16) szx[wave][j][lane] = zz;
      Zb[j] = zz;
    }
    __syncthreads();
    if (wm == 0 && lane < 16){
#pragma unroll
      for (int j = 0; j < 4; ++j){
        const int gc = n0 + wn*64 + j*16 + lane;
        size_t o = ((size_t)b * NQS + bx) * TT + gc;
        f0[o] = Mb[j];
        f1[o] = Zb[j] + szx[wave + 2][j][lane];
      }
    }
  }
}

// ------- merge NQS partials; emit c[rb][t] = exp(pm - M) * zinv as f16 -------
__global__ __launch_bounds__(256)
void statsB_kernel(const float* __restrict__ pm, const float* __restrict__ pz,
                   f16* __restrict__ c){
  const int b = blockIdx.y;
  const int t = blockIdx.x * 256 + threadIdx.x;
  float am[NQS], az[NQS];
#pragma unroll
  for (int k = 0; k < NQS; ++k){
    size_t o = ((size_t)b * NQS + k) * TT + t;
    am[k] = pm[o]; az[k] = pz[o];
  }
  float M = am[0];
#pragma unroll
  for (int k = 1; k < NQS; ++k) M = fmaxf(M, am[k]);
  float Z = 0.f;
#pragma unroll
  for (int k = 0; k < NQS; ++k) Z += az[k] * __expf(am[k] - M);
  const float zi = 1.f / (Z * 27.712812921102035f);  // 1/(Z*sqrt(768))
#pragma unroll
  for (int k = 0; k < NQS; ++k)
    c[((size_t)b * NQS + k) * TT + t] = (f16)(__expf(am[k] - M) * zi);
}

// ---------------- V [t,v] -> Vt [v,t] (per local batch z) ----------------
__global__ __launch_bounds__(256)
void transp_kernel(const u16* __restrict__ V, u16* __restrict__ Vt){
  const int b = blockIdx.z;
  const int t0 = blockIdx.x * 64, v0 = blockIdx.y * 64;
  const u16* Vb = V + (size_t)b * TT * DD;
  u16* Vtb = Vt + (size_t)b * DD * TT;
  __shared__ u16 tile[64][66];
  const int tid = threadIdx.x;
#pragma unroll
  for (int i = 0; i < 4; ++i){
    int cI = i*256 + tid;
    int r = cI >> 4, c4 = (cI & 15) * 4;
    ushort4 u = *(const ushort4*)&Vb[(size_t)(t0 + r) * DD + v0 + c4];
    tile[r][c4+0] = u.x; tile[r][c4+1] = u.y; tile[r][c4+2] = u.z; tile[r][c4+3] = u.w;
  }
  __syncthreads();
#pragma unroll
  for (int i = 0; i < 4; ++i){
    int cI = i*256 + tid;
    int vr = cI >> 4, t4 = (cI & 15) * 4;
    ushort4 u;
    u.x = tile[t4+0][vr]; u.y = tile[t4+1][vr]; u.z = tile[t4+2][vr]; u.w = tile[t4+3][vr];
    *(ushort4*)&Vtb[(size_t)(v0 + vr) * TT + t0 + t4] = u;
  }
}

// ------- residual + LayerNorm: out = LN(applied_f16 + x) -------
__global__ __launch_bounds__(192)
void ln2_kernel(const half4* __restrict__ applied, const float4* __restrict__ x,
                const float4* __restrict__ gamma4, const float4* __restrict__ beta4,
                float4* __restrict__ out){
  const size_t base = (size_t)blockIdx.x * (DD/4);
  const int cc = threadIdx.x;          // 0..191
  half4 a4 = applied[base + cc];
  float4 x4 = x[base + cc];
  float y0 = (float)a4[0] + x4.x;
  float y1 = (float)a4[1] + x4.y;
  float y2 = (float)a4[2] + x4.z;
  float y3 = (float)a4[3] + x4.w;
  float s = y0+y1+y2+y3;
  float sq = y0*y0+y1*y1+y2*y2+y3*y3;
#pragma unroll
  for (int off = 32; off > 0; off >>= 1){
    s  += __shfl_down(s,  off, 64);
    sq += __shfl_down(sq, off, 64);
  }
  __shared__ float rs_[3], rq_[3];
  const int lane = threadIdx.x & 63, w = threadIdx.x >> 6;
  if (lane == 0){ rs_[w] = s; rq_[w] = sq; }
  __syncthreads();
  const float S_ = rs_[0]+rs_[1]+rs_[2];
  const float Q_ = rq_[0]+rq_[1]+rq_[2];
  const float mu  = S_ * (1.f/DD);
  const float var = Q_ * (1.f/DD) - mu*mu;
  const float rstd = rsqrtf(var + 1e-5f);
  float4 g = gamma4[cc], be = beta4[cc], o;
  o.x = (y0 - mu)*rstd*g.x + be.x;
  o.y = (y1 - mu)*rstd*g.y + be.y;
  o.z = (y2 - mu)*rstd*g.z + be.z;
  o.w = (y3 - mu)*rstd*g.w + be.w;
  out[base + cc] = o;
}

extern "C" void kernel_launch(void* const* d_in, const int* in_sizes, int n_in,
                              void* d_out, int out_size, void* d_ws, size_t ws_size,
                              hipStream_t stream)
{
  const float* x    = (const float*)d_in[0];
  const float* Wk   = (const float*)d_in[1];
  const float* bk   = (const float*)d_in[2];
  const float* Wq   = (const float*)d_in[3];
  const float* bq   = (const float*)d_in[4];
  const float* Wv   = (const float*)d_in[5];
  const float* bv   = (const float*)d_in[6];
  const float* gamma= (const float*)d_in[7];
  const float* beta = (const float*)d_in[8];
  float* out = (float*)d_out;

  const size_t PW = (size_t)DD*DD*2;    // f16 weight plane
  const size_t PB = (size_t)TT*DD*2;    // f16 activation plane per batch
  const size_t T4 = (size_t)TT*4;
  auto al = [](size_t n){ return (n + 255) & ~(size_t)255; };

  auto need = [&](int G)->size_t{
    size_t t = al(3*PW) + al(3*DD*4) + al((size_t)BB*PB) + al((size_t)BB*TT*TT*2)
             + al((size_t)G*PB) + al(3*(size_t)G*PB)
             + 2*al((size_t)G*NQS*T4) + al((size_t)BB*NQS*TT*2);
    if (4*(size_t)G*PB < (size_t)BB*PB) t += al((size_t)BB*PB);  // applied alias shortfall
    return t;
  };

  int G = 0;
  for (int g : {16, 8, 4, 2, 1}) if (need(g) <= ws_size){ G = g; break; }
  if (G == 0) return;

  char* p = (char*)d_ws;
  auto alloc = [&](size_t n)->char*{ char* r = p; p += (n + 255) & ~(size_t)255; return r; };
  f16*   Wf    = (f16*)alloc(3*PW);            // [Wq;Wk;Wv]
  float* biasf = (float*)alloc(3*DD*4);        // [bq;bk;bv]
  f16*   Vt    = (f16*)alloc((size_t)BB*PB);
  f16*   P16   = (f16*)alloc((size_t)BB*TT*TT*2);
  f16*   Xc    = (f16*)alloc((size_t)G*PB);
  f16*   QKVc  = (f16*)alloc(3*(size_t)G*PB);
  float* pm    = (float*)alloc((size_t)G*NQS*T4);
  float* pz    = (float*)alloc((size_t)G*NQS*T4);
  f16*   cbuf  = (f16*)alloc((size_t)BB*NQS*TT*2);
  // applied (BB*PB) lives over Xc+QKVc (contiguous, dead at PV time) when it fits
  f16* applied = (4*(size_t)G*PB >= (size_t)BB*PB) ? Xc
               : (f16*)alloc((size_t)BB*PB);
  f16* Qc = QKVc, *Kc = QKVc + (size_t)G*TT*DD, *Vc = QKVc + 2*(size_t)G*TT*DD;

  tofp16_kernel<<<288, 256, 0, stream>>>(Wq, Wf,             DD*DD/4);
  tofp16_kernel<<<288, 256, 0, stream>>>(Wk, Wf +   DD*DD,   DD*DD/4);
  tofp16_kernel<<<288, 256, 0, stream>>>(Wv, Wf + 2*DD*DD,   DD*DD/4);
  hipMemcpyAsync(biasf,        bq, DD*4, hipMemcpyDeviceToDevice, stream);
  hipMemcpyAsync(biasf +   DD, bk, DD*4, hipMemcpyDeviceToDevice, stream);
  hipMemcpyAsync(biasf + 2*DD, bv, DD*4, hipMemcpyDeviceToDevice, stream);

  const int nRows = G * TT;
  for (int b0 = 0; b0 < BB; b0 += G){
    tofp16_kernel<<<2048, 256, 0, stream>>>(x + (size_t)b0*TT*DD, Xc, nRows*DD/4);

    // merged Q,K,V projections: z = proj index (256x128 engine)
    dim3 gp(nRows/256, DD/128, 3);
    gemmk<0><<<gp, 256, 0, stream>>>(Xc, DD, 0, Wf, DD, (long)DD*DD,
                                     QKVc, DD, (long)G*TT*DD, biasf, DD,
                                     nullptr, nullptr, nullptr);

    transp_kernel<<<dim3(TT/64, DD/64, G), 256, 0, stream>>>(
        (const u16*)Vc, (u16*)(Vt + (size_t)b0*DD*TT));

    // S = Q K^T -> P'' f16 directly into P16, + stats partials (256x128 engine)
    dim3 gs(TT/256, TT/128, G);
    gemmk<1><<<gs, 256, 0, stream>>>(Qc, DD, (long)TT*DD, Kc, DD, (long)TT*DD,
                                     P16 + (size_t)b0*TT*TT, TT, (long)TT*TT,
                                     nullptr, DD, pm, pz, nullptr);

    statsB_kernel<<<dim3(TT/256, G), 256, 0, stream>>>(
        pm, pz, cbuf + (size_t)b0*NQS*TT);
  }

  // PV over all batches -> applied f16 (128x128 engine, correction folded into A)
  dim3 gpv(TT/128, DD/128, BB);
  gemmk<2><<<gpv, 256, 0, stream>>>(P16, TT, (long)TT*TT, Vt, TT, (long)DD*TT,
                                    applied, DD, (long)TT*DD, nullptr, TT,
                                    nullptr, nullptr, cbuf);

  ln2_kernel<<<BT, 192, 0, stream>>>((const half4*)applied, (const float4*)x,
                                     (const float4*)gamma, (const float4*)beta,
                                     (float4*)out);
}

// Round 12
// 538.757 us; speedup vs baseline: 1.7311x; 1.0446x over previous
//
#include <hip/hip_runtime.h>
#include <hip/hip_fp16.h>

// Problem constants (reference: B=16, T=2048, D=768)
#define DD 768
#define BB 16
#define TT 2048
#define BT (BB*TT)   // 32768
#define NQS 8        // 256-row blocks per batch for column-softmax stats
#define BST 76       // bounce tile stride (f16): conflict-free write+read phases

using f16 = _Float16;
typedef __attribute__((ext_vector_type(8))) f16 half8;   // MFMA A/B frag (4 VGPR)
typedef __attribute__((ext_vector_type(4))) f16 half4;   // 8B
typedef __attribute__((ext_vector_type(4))) float f32x4; // MFMA C/D frag

// XOR involution on 16B slots within a row: spreads K-slots across banks
#define GSWZ(r) ((((r) & 3)) ^ (((r) >> 2) & 3))

typedef const __attribute__((address_space(1))) unsigned int* gas1;
typedef __attribute__((address_space(3))) unsigned int* las3;
__device__ __forceinline__ void gload16(const void* g, void* l){
  __builtin_amdgcn_global_load_lds((gas1)g, (las3)l, 16, 0, 0);
}

// ---------------- fp32 -> fp16 ----------------
__global__ __launch_bounds__(256)
void tofp16_kernel(const float* __restrict__ src, f16* __restrict__ dst, int n4){
  const int stride = gridDim.x * 256;
  for (int i = blockIdx.x*256 + threadIdx.x; i < n4; i += stride){
    float4 v = ((const float4*)src)[i];
    half4 h; h[0]=(f16)v.x; h[1]=(f16)v.y; h[2]=(f16)v.z; h[3]=(f16)v.w;
    ((half4*)dst)[i] = h;
  }
}

// =================================================================
// NT GEMM engine, 256 threads (4 waves 2Mx2N), BK=32, 3-deep LDS
// pipeline, counted vmcnt, XCD swizzle (A-panel reuse), LDS-bounce
// vectorized epilogue (16B stores; proj-V writes Vt transposed).
//   OMODE 0 (QKV proj)  : 256x128 block, 8x4 acc/wave, 2 blocks/CU
//   OMODE 1 (S -> P'')  : 256x128 block, 8x4 acc/wave, 2 blocks/CU
//   OMODE 2 (PV)        : 128x128 block, 4x4 acc/wave, 3 blocks/CU
// =================================================================
template<int OMODE>
__global__ __launch_bounds__(256, OMODE==2 ? 3 : 2)
void gemmk(const f16* __restrict__ A, int lda, long sA,
           const f16* __restrict__ B, int ldb, long sB,
           void* __restrict__ Out, int ldc, long sC,
           const float* __restrict__ aux, int Kdim,
           float* __restrict__ f0, float* __restrict__ f1,
           const f16* __restrict__ cs, f16* __restrict__ vt)
{
  constexpr int MR = (OMODE==2) ? 4 : 8;   // m-frag reps per wave
  constexpr int BM = MR * 32;              // block rows (128 or 256)
  constexpr int AC = BM / 64;              // A staging chunks per thread

  __shared__ f16 lA[3][BM*32];             // 24 or 48 KB
  __shared__ f16 lB[3][128*32];            // 24 KB
  __shared__ float smx[OMODE==1 ? 4 : 1][4][16], szx[OMODE==1 ? 4 : 1][4][16];
  __shared__ f16 lCC[OMODE==2 ? 2048 : 8]; // softmax-correction row (PV)

  // XCD swizzle (nwg % 8 == 0 on all our grids): XCD k owns a contiguous
  // work range decoded by-FASTEST so consecutive works share the A-panel.
  const int nx = gridDim.x, ny = gridDim.y, nwg = nx * ny, cpx = nwg >> 3;
  int h = blockIdx.x + nx * blockIdx.y;
  h = (h & 7) * cpx + (h >> 3);
  const int bx = h / ny, by = h % ny;

  const int b = blockIdx.z;
  const f16* A_ = A + (size_t)b * sA;
  const f16* B_ = B + (size_t)b * sB;
  const int m0 = bx * BM, n0 = by * 128;
  const int tid = threadIdx.x, lane = tid & 63, wave = tid >> 6;
  const int wm = wave >> 1, wn = wave & 1;

  // staging: chunk c -> row=c>>2, dest slot c&3 (LDS linear),
  // SOURCE slot = (c&3) ^ GSWZ(row)  [involution]
  size_t gaO[AC], gbO[2];
#pragma unroll
  for (int k = 0; k < AC; ++k){
    int c = k*256 + tid, r = c >> 2, s = (c & 3) ^ GSWZ(r);
    gaO[k] = (size_t)(m0 + r) * lda + s * 8;
  }
#pragma unroll
  for (int k = 0; k < 2; ++k){
    int c = k*256 + tid, r = c >> 2, s = (c & 3) ^ GSWZ(r);
    gbO[k] = (size_t)(n0 + r) * ldb + s * 8;
  }

  f32x4 acc[MR][4] = {};
  const int NT = Kdim >> 5;

  auto STAGE = [&](int u, int kt){
#pragma unroll
    for (int k = 0; k < AC; ++k) gload16(A_ + gaO[k] + kt, &lA[u][(k*256+tid)*8]);
#pragma unroll
    for (int k = 0; k < 2; ++k)  gload16(B_ + gbO[k] + kt, &lB[u][(k*256+tid)*8]);
  };

  if constexpr (OMODE == 2){
    // preload softmax-correction row: stats rb = bx>>1 (256-row stats blocks)
    const f16* cb = cs + ((size_t)b * NQS + (bx >> 1)) * TT;
    ((half8*)lCC)[tid] = ((const half8*)cb)[tid];
    __syncthreads();
  }

  STAGE(0, 0); STAGE(1, 32);   // 2 tiles ahead in flight

  const int frow = lane & 15;
  const int rsl = (((lane >> 4) ^ GSWZ(frow)) & 3) * 8;   // swizzled LDS slot
  const int tsl = (lane >> 4) * 8;                        // logical K slot
  const int offA = (wm*(MR*16) + frow)*32 + rsl;
  const int offB = (wn*64 + frow)*32 + rsl;

  int u = 0;
  for (int t = 0; t < NT; ++t){
    int u2 = u + 2; if (u2 >= 3) u2 -= 3;
    __builtin_amdgcn_s_barrier();            // readers of buf[u2] (iter t-1) done
    __builtin_amdgcn_sched_barrier(0);
    if (t + 2 < NT) STAGE(u2, (t + 2) * 32);
    const int rem = NT - 1 - t;
    if constexpr (AC == 4){   // 6 loads/tile
      if (rem >= 2)      asm volatile("s_waitcnt vmcnt(12)" ::: "memory");
      else if (rem == 1) asm volatile("s_waitcnt vmcnt(6)"  ::: "memory");
      else               asm volatile("s_waitcnt vmcnt(0)"  ::: "memory");
    } else {                  // 4 loads/tile
      if (rem >= 2)      asm volatile("s_waitcnt vmcnt(8)" ::: "memory");
      else if (rem == 1) asm volatile("s_waitcnt vmcnt(4)" ::: "memory");
      else               asm volatile("s_waitcnt vmcnt(0)" ::: "memory");
    }
    __builtin_amdgcn_s_barrier();            // tile-t landed for all waves
    __builtin_amdgcn_sched_barrier(0);

    const f16* tA = &lA[u][0] + offA;
    const f16* tB = &lB[u][0] + offB;
    half8 af[MR], bf[4];
#pragma unroll
    for (int i = 0; i < MR; ++i) af[i] = *(const half8*)(tA + i*512);
#pragma unroll
    for (int j = 0; j < 4; ++j)  bf[j] = *(const half8*)(tB + j*512);
    if constexpr (OMODE == 2){
      half8 cc = *(const half8*)&lCC[t*32 + tsl];   // P = P'' * c, folded into A
#pragma unroll
      for (int i = 0; i < MR; ++i) af[i] *= cc;
    }
    __builtin_amdgcn_s_setprio(1);
#pragma unroll
    for (int i = 0; i < MR; ++i)
#pragma unroll
      for (int j = 0; j < 4; ++j)
        acc[i][j] = __builtin_amdgcn_mfma_f32_16x16x32_f16(af[i], bf[j], acc[i][j], 0,0,0);
    __builtin_amdgcn_s_setprio(0);
    u = (u + 1 == 3) ? 0 : u + 1;
  }

  // ============ epilogue: LDS-bounce vectorized stores ============
  // C/D layout: col = lane&15, row = (lane>>4)*4 + r  [m89 verified].
  // Bounce [16][BST] f16 per wave (conflict-free both phases), 16B stores.
  __syncthreads();   // all waves done reading pipeline LDS; safe to reuse
  const int kq4 = (lane >> 4) * 4;
  f16* bnc = &lA[0][0] + wave * (16*BST);
  const int rrow = lane >> 2, rcol = (lane & 3) * 16;   // read-phase mapping

  if constexpr (OMODE == 0 || OMODE == 2){
    const bool toVt = (OMODE == 0) && (b == 2);
    float bias4[4] = {};
    if constexpr (OMODE == 0){
#pragma unroll
      for (int j = 0; j < 4; ++j) bias4[j] = aux[b*DD + n0 + wn*64 + j*16 + frow];
    }
    f16* O = (OMODE == 0) ? ((f16*)Out + (size_t)b * sC) : ((f16*)Out + (size_t)b * sC);
#pragma unroll
    for (int i = 0; i < MR; ++i){
#pragma unroll
      for (int j = 0; j < 4; ++j)
#pragma unroll
        for (int r = 0; r < 4; ++r)
          bnc[(kq4 + r)*BST + j*16 + frow] = (f16)(acc[i][j][r] + bias4[j]);
      if (!toVt){
        half8 w0 = *(const half8*)&bnc[rrow*BST + rcol];
        half8 w1 = *(const half8*)&bnc[rrow*BST + rcol + 8];
        const int gr = m0 + wm*(MR*16) + i*16 + rrow;
        const int gc = n0 + wn*64 + rcol;
        *(half8*)&O[(size_t)gr*ldc + gc]     = w0;
        *(half8*)&O[(size_t)gr*ldc + gc + 8] = w1;
      } else {
        // V projection -> Vt[batch][v][token], 32B-contiguous token strips
        f16 tmp[16];
#pragma unroll
        for (int k = 0; k < 16; ++k) tmp[k] = bnc[k*BST + lane];
        half8 v0, v1;
#pragma unroll
        for (int k = 0; k < 8; ++k){ v0[k] = tmp[k]; v1[k] = tmp[8+k]; }
        const int tokg = m0 + wm*(MR*16) + i*16;
        const int batch = tokg >> 11, tok = tokg & (TT-1);
        f16* Vo = vt + ((size_t)batch*DD + n0 + wn*64 + lane)*TT + tok;
        *(half8*)&Vo[0] = v0;
        *(half8*)&Vo[8] = v1;
      }
    }
  } else {
    // S -> P'' = exp(S - M_blk) f16, + per-(256-rowblock,column) partials
    f16* O = (f16*)Out + (size_t)b * sC;
    float Mb[4];
#pragma unroll
    for (int j = 0; j < 4; ++j){
      float mx = acc[0][j][0];
#pragma unroll
      for (int i = 0; i < MR; ++i)
#pragma unroll
        for (int r = 0; r < 4; ++r) mx = fmaxf(mx, acc[i][j][r]);
      mx = fmaxf(mx, __shfl_xor(mx, 16, 64));
      mx = fmaxf(mx, __shfl_xor(mx, 32, 64));
      if (lane < 16) smx[wave][j][lane] = mx;
      Mb[j] = mx;
    }
    __syncthreads();
#pragma unroll
    for (int j = 0; j < 4; ++j)
      Mb[j] = fmaxf(Mb[j], smx[wave ^ 2][j][frow]);   // block-level column max
    float zz[4] = {};
#pragma unroll
    for (int i = 0; i < MR; ++i){
#pragma unroll
      for (int j = 0; j < 4; ++j)
#pragma unroll
        for (int r = 0; r < 4; ++r){
          float e = __expf(acc[i][j][r] - Mb[j]);
          zz[j] += e;
          bnc[(kq4 + r)*BST + j*16 + frow] = (f16)e;
        }
      half8 w0 = *(const half8*)&bnc[rrow*BST + rcol];
      half8 w1 = *(const half8*)&bnc[rrow*BST + rcol + 8];
      const int gr = m0 + wm*(MR*16) + i*16 + rrow;
      const int gc = n0 + wn*64 + rcol;
      *(half8*)&O[(size_t)gr*ldc + gc]     = w0;
      *(half8*)&O[(size_t)gr*ldc + gc + 8] = w1;
    }
#pragma unroll
    for (int j = 0; j < 4; ++j){
      zz[j] += __shfl_xor(zz[j], 16, 64);
      zz[j] += __shfl_xor(zz[j], 32, 64);
      if (lane < 16) szx[wave][j][lane] = zz[j];
    }
    __syncthreads();
    if (wm == 0 && lane < 16){
#pragma unroll
      for (int j = 0; j < 4; ++j){
        const int gc = n0 + wn*64 + j*16 + lane;
        size_t o = ((size_t)b * NQS + bx) * TT + gc;
        f0[o] = Mb[j];   // NB: Mb uniform across frow==lane here? no: recompute
        f1[o] = zz[j] + szx[wave + 2][j][lane];
      }
    }
  }
}

// ------- merge NQS partials; emit c[rb][t] = exp(pm - M) * zinv as f16 -------
__global__ __launch_bounds__(256)
void statsB_kernel(const float* __restrict__ pm, const float* __restrict__ pz,
                   f16* __restrict__ c){
  const int b = blockIdx.y;
  const int t = blockIdx.x * 256 + threadIdx.x;
  float am[NQS], az[NQS];
#pragma unroll
  for (int k = 0; k < NQS; ++k){
    size_t o = ((size_t)b * NQS + k) * TT + t;
    am[k] = pm[o]; az[k] = pz[o];
  }
  float M = am[0];
#pragma unroll
  for (int k = 1; k < NQS; ++k) M = fmaxf(M, am[k]);
  float Z = 0.f;
#pragma unroll
  for (int k = 0; k < NQS; ++k) Z += az[k] * __expf(am[k] - M);
  const float zi = 1.f / (Z * 27.712812921102035f);  // 1/(Z*sqrt(768))
#pragma unroll
  for (int k = 0; k < NQS; ++k)
    c[((size_t)b * NQS + k) * TT + t] = (f16)(__expf(am[k] - M) * zi);
}

// ------- residual + LayerNorm: out = LN(applied_f16 + x) -------
__global__ __launch_bounds__(192)
void ln2_kernel(const half4* __restrict__ applied, const float4* __restrict__ x,
                const float4* __restrict__ gamma4, const float4* __restrict__ beta4,
                float4* __restrict__ out){
  const size_t base = (size_t)blockIdx.x * (DD/4);
  const int cc = threadIdx.x;          // 0..191
  half4 a4 = applied[base + cc];
  float4 x4 = x[base + cc];
  float y0 = (float)a4[0] + x4.x;
  float y1 = (float)a4[1] + x4.y;
  float y2 = (float)a4[2] + x4.z;
  float y3 = (float)a4[3] + x4.w;
  float s = y0+y1+y2+y3;
  float sq = y0*y0+y1*y1+y2*y2+y3*y3;
#pragma unroll
  for (int off = 32; off > 0; off >>= 1){
    s  += __shfl_down(s,  off, 64);
    sq += __shfl_down(sq, off, 64);
  }
  __shared__ float rs_[3], rq_[3];
  const int lane = threadIdx.x & 63, w = threadIdx.x >> 6;
  if (lane == 0){ rs_[w] = s; rq_[w] = sq; }
  __syncthreads();
  const float S_ = rs_[0]+rs_[1]+rs_[2];
  const float Q_ = rq_[0]+rq_[1]+rq_[2];
  const float mu  = S_ * (1.f/DD);
  const float var = Q_ * (1.f/DD) - mu*mu;
  const float rstd = rsqrtf(var + 1e-5f);
  float4 g = gamma4[cc], be = beta4[cc], o;
  o.x = (y0 - mu)*rstd*g.x + be.x;
  o.y = (y1 - mu)*rstd*g.y + be.y;
  o.z = (y2 - mu)*rstd*g.z + be.z;
  o.w = (y3 - mu)*rstd*g.w + be.w;
  out[base + cc] = o;
}

extern "C" void kernel_launch(void* const* d_in, const int* in_sizes, int n_in,
                              void* d_out, int out_size, void* d_ws, size_t ws_size,
                              hipStream_t stream)
{
  const float* x    = (const float*)d_in[0];
  const float* Wk   = (const float*)d_in[1];
  const float* bk   = (const float*)d_in[2];
  const float* Wq   = (const float*)d_in[3];
  const float* bq   = (const float*)d_in[4];
  const float* Wv   = (const float*)d_in[5];
  const float* bv   = (const float*)d_in[6];
  const float* gamma= (const float*)d_in[7];
  const float* beta = (const float*)d_in[8];
  float* out = (float*)d_out;

  const size_t PW = (size_t)DD*DD*2;    // f16 weight plane
  const size_t PB = (size_t)TT*DD*2;    // f16 activation plane per batch
  const size_t T4 = (size_t)TT*4;
  auto al = [](size_t n){ return (n + 255) & ~(size_t)255; };

  auto need = [&](int G)->size_t{
    size_t t = al(3*PW) + al(3*DD*4) + al((size_t)BB*PB) + al((size_t)BB*TT*TT*2)
             + al((size_t)G*PB) + al(2*(size_t)G*PB)
             + 2*al((size_t)G*NQS*T4) + al((size_t)BB*NQS*TT*2);
    if (3*(size_t)G*PB < (size_t)BB*PB) t += al((size_t)BB*PB);  // applied alias shortfall
    return t;
  };

  int G = 0;
  for (int g : {16, 8, 4, 2, 1}) if (need(g) <= ws_size){ G = g; break; }
  if (G == 0) return;

  char* p = (char*)d_ws;
  auto alloc = [&](size_t n)->char*{ char* r = p; p += (n + 255) & ~(size_t)255; return r; };
  f16*   Wf    = (f16*)alloc(3*PW);            // [Wq;Wk;Wv]
  float* biasf = (float*)alloc(3*DD*4);        // [bq;bk;bv]
  f16*   Vt    = (f16*)alloc((size_t)BB*PB);
  f16*   P16   = (f16*)alloc((size_t)BB*TT*TT*2);
  f16*   Xc    = (f16*)alloc((size_t)G*PB);
  f16*   QKVc  = (f16*)alloc(2*(size_t)G*PB);  // Q,K planes only (V -> Vt direct)
  float* pm    = (float*)alloc((size_t)G*NQS*T4);
  float* pz    = (float*)alloc((size_t)G*NQS*T4);
  f16*   cbuf  = (f16*)alloc((size_t)BB*NQS*TT*2);
  // applied (BB*PB) lives over Xc+QKVc (contiguous, dead at PV time) when it fits
  f16* applied = (3*(size_t)G*PB >= (size_t)BB*PB) ? Xc
               : (f16*)alloc((size_t)BB*PB);
  f16* Qc = QKVc, *Kc = QKVc + (size_t)G*TT*DD;

  tofp16_kernel<<<288, 256, 0, stream>>>(Wq, Wf,             DD*DD/4);
  tofp16_kernel<<<288, 256, 0, stream>>>(Wk, Wf +   DD*DD,   DD*DD/4);
  tofp16_kernel<<<288, 256, 0, stream>>>(Wv, Wf + 2*DD*DD,   DD*DD/4);
  hipMemcpyAsync(biasf,        bq, DD*4, hipMemcpyDeviceToDevice, stream);
  hipMemcpyAsync(biasf +   DD, bk, DD*4, hipMemcpyDeviceToDevice, stream);
  hipMemcpyAsync(biasf + 2*DD, bv, DD*4, hipMemcpyDeviceToDevice, stream);

  const int nRows = G * TT;
  for (int b0 = 0; b0 < BB; b0 += G){
    tofp16_kernel<<<2048, 256, 0, stream>>>(x + (size_t)b0*TT*DD, Xc, nRows*DD/4);

    // merged Q,K,V projections: z = proj index; V writes Vt transposed in-epilogue
    dim3 gp(nRows/256, DD/128, 3);
    gemmk<0><<<gp, 256, 0, stream>>>(Xc, DD, 0, Wf, DD, (long)DD*DD,
                                     QKVc, DD, (long)G*TT*DD, biasf, DD,
                                     nullptr, nullptr, nullptr,
                                     Vt + (size_t)b0*DD*TT);

    // S = Q K^T -> P'' f16 directly into P16, + stats partials
    dim3 gs(TT/256, TT/128, G);
    gemmk<1><<<gs, 256, 0, stream>>>(Qc, DD, (long)TT*DD, Kc, DD, (long)TT*DD,
                                     P16 + (size_t)b0*TT*TT, TT, (long)TT*TT,
                                     nullptr, DD, pm, pz, nullptr, nullptr);

    statsB_kernel<<<dim3(TT/256, G), 256, 0, stream>>>(
        pm, pz, cbuf + (size_t)b0*NQS*TT);
  }

  // PV over all batches -> applied f16 (correction folded into A-frags)
  dim3 gpv(TT/128, DD/128, BB);
  gemmk<2><<<gpv, 256, 0, stream>>>(P16, TT, (long)TT*TT, Vt, TT, (long)DD*TT,
                                    applied, DD, (long)TT*DD, nullptr, TT,
                                    nullptr, nullptr, cbuf, nullptr);

  ln2_kernel<<<BT, 192, 0, stream>>>((const half4*)applied, (const float4*)x,
                                     (const float4*)gamma, (const float4*)beta,
                                     (float4*)out);
}